// Round 8
// baseline (1297.625 us; speedup 1.0000x reference)
//
#include <hip/hip_runtime.h>
#include <math.h>

#define N_NODES 50000
#define N_EDGES 800000
#define N_ETOT  850000   /* E + N self-loops */
#define F_IN    32
#define HEADS   4
#define CHAN    64
#define HID     256
#define NGRAPH  1024
#define MLP_HID 2048
#define NOUT    768
#define NEG_SLOPE 0.2f

// ---------------------------------------------------------------- CSR build
__global__ __launch_bounds__(256) void hist_kernel(const int* __restrict__ ei,
                                                   int* __restrict__ deg) {
    int e = blockIdx.x * 256 + threadIdx.x;
    if (e >= N_ETOT) return;
    int d = (e < N_EDGES) ? ei[N_EDGES + e] : (e - N_EDGES);
    atomicAdd(&deg[d], 1);
}

__global__ __launch_bounds__(1024) void scan_kernel(const int* __restrict__ deg,
                                                    int* __restrict__ off,
                                                    int* __restrict__ cur) {
    __shared__ int sums[1024];
    const int t = threadIdx.x;
    const int CHK = (N_NODES + 1023) / 1024;   // 49
    int lo = t * CHK;
    int hi = min(lo + CHK, N_NODES);
    int s = 0;
    for (int i = lo; i < hi; ++i) s += deg[i];
    sums[t] = s;
    __syncthreads();
    for (int d = 1; d < 1024; d <<= 1) {
        int v = (t >= d) ? sums[t - d] : 0;
        __syncthreads();
        sums[t] += v;
        __syncthreads();
    }
    int run = sums[t] - s;                     // exclusive prefix
    for (int i = lo; i < hi; ++i) {
        int d0 = deg[i];
        off[i] = run;
        cur[i] = run;
        run += d0;
    }
    if (t == 1023) off[N_NODES] = run;
}

__global__ __launch_bounds__(256) void scatter_kernel(const int* __restrict__ ei,
                                                      int* __restrict__ cur,
                                                      int* __restrict__ ssrc) {
    int e = blockIdx.x * 256 + threadIdx.x;
    if (e >= N_ETOT) return;
    int s, d;
    if (e < N_EDGES) { s = ei[e]; d = ei[N_EDGES + e]; }
    else             { s = e - N_EDGES; d = s; }
    int pos = atomicAdd(&cur[d], 1);
    ssrc[pos] = s;
}

// ---------------------------------------------------------------- fp32 GEMM
// C[M,Nn] = A[M,K] @ B[K,Nn] (+bias)(+relu).
// Register-prefetch double buffer: tile k+1 is loaded to regs while tile k
// computes from LDS. As stored transposed As[k][m]; both fragments read as
// ds_read_b128. 256 threads, TMxTN micro-tile.
template <int BM, int BN, int BK, int TM, int TN, bool BIAS, bool RELU>
__global__ __launch_bounds__(256) void gemm_kernel(const float* __restrict__ A,
                                                   const float* __restrict__ B,
                                                   const float* __restrict__ bias,
                                                   float* __restrict__ C,
                                                   int M, int Nn, int K) {
    __shared__ float As[BK][BM + 4];
    __shared__ float Bs[BK][BN + 4];
    const int t = threadIdx.x;
    const int bm = blockIdx.x * BM;
    const int bn = blockIdx.y * BN;
    constexpr int NTX = BN / TN;               // threads along N
    const int tx = t % NTX;
    const int ty = t / NTX;
    const int row0 = ty * TM;
    const int col0 = tx * TN;
    constexpr int BK4 = BK / 4;
    constexpr int BN4 = BN / 4;
    constexpr int AITER = BM * BK4 / 256;      // float4s per thread for A tile
    constexpr int BITER = BK * BN4 / 256;

    float4 aReg[AITER], bReg[BITER];

    // ---- prologue: load tile 0 into regs
    #pragma unroll
    for (int it = 0; it < AITER; ++it) {
        int f = t + it * 256;
        int m = f / BK4, kq = (f % BK4) * 4;
        int gr = bm + m;
        aReg[it] = (gr < M) ? *(const float4*)&A[(size_t)gr * K + kq]
                            : make_float4(0.f, 0.f, 0.f, 0.f);
    }
    #pragma unroll
    for (int it = 0; it < BITER; ++it) {
        int f = t + it * 256;
        int k = f / BN4, n = (f % BN4) * 4;
        bReg[it] = *(const float4*)&B[(size_t)k * Nn + bn + n];
    }

    float acc[TM][TN] = {};
    for (int k0 = 0; ; ) {
        // ---- regs -> LDS
        #pragma unroll
        for (int it = 0; it < AITER; ++it) {
            int f = t + it * 256;
            int m = f / BK4, kq = (f % BK4) * 4;
            As[kq + 0][m] = aReg[it].x;
            As[kq + 1][m] = aReg[it].y;
            As[kq + 2][m] = aReg[it].z;
            As[kq + 3][m] = aReg[it].w;
        }
        #pragma unroll
        for (int it = 0; it < BITER; ++it) {
            int f = t + it * 256;
            int k = f / BN4, n = (f % BN4) * 4;
            *(float4*)&Bs[k][n] = bReg[it];
        }
        __syncthreads();

        // ---- issue prefetch of next tile (overlaps compute below)
        const int knext = k0 + BK;
        if (knext < K) {
            #pragma unroll
            for (int it = 0; it < AITER; ++it) {
                int f = t + it * 256;
                int m = f / BK4, kq = (f % BK4) * 4;
                int gr = bm + m;
                aReg[it] = (gr < M) ? *(const float4*)&A[(size_t)gr * K + knext + kq]
                                    : make_float4(0.f, 0.f, 0.f, 0.f);
            }
            #pragma unroll
            for (int it = 0; it < BITER; ++it) {
                int f = t + it * 256;
                int k = f / BN4, n = (f % BN4) * 4;
                bReg[it] = *(const float4*)&B[(size_t)(knext + k) * Nn + bn + n];
            }
        }

        // ---- compute from LDS
        #pragma unroll
        for (int k = 0; k < BK; ++k) {
            float a[TM], b[TN];
            #pragma unroll
            for (int i = 0; i < TM; i += 4)
                *(float4*)&a[i] = *(const float4*)&As[k][row0 + i];
            #pragma unroll
            for (int j = 0; j < TN; j += 4)
                *(float4*)&b[j] = *(const float4*)&Bs[k][col0 + j];
            #pragma unroll
            for (int i = 0; i < TM; ++i)
                #pragma unroll
                for (int j = 0; j < TN; ++j)
                    acc[i][j] += a[i] * b[j];
        }
        k0 = knext;
        if (k0 >= K) break;
        __syncthreads();                       // LDS reuse barrier
    }

    #pragma unroll
    for (int i = 0; i < TM; ++i) {
        int r = bm + row0 + i;
        if (r >= M) continue;
        #pragma unroll
        for (int j = 0; j < TN; j += 4) {
            int c = bn + col0 + j;
            float4 v;
            v.x = acc[i][j + 0];
            v.y = acc[i][j + 1];
            v.z = acc[i][j + 2];
            v.w = acc[i][j + 3];
            if (BIAS) {
                const float4 bv = *(const float4*)&bias[c];
                v.x += bv.x; v.y += bv.y; v.z += bv.z; v.w += bv.w;
            }
            if (RELU) {
                v.x = fmaxf(v.x, 0.f); v.y = fmaxf(v.y, 0.f);
                v.z = fmaxf(v.z, 0.f); v.w = fmaxf(v.w, 0.f);
            }
            *(float4*)&C[(size_t)r * Nn + c] = v;
        }
    }
}

// ------------------------------------------------------- attention logits
__global__ __launch_bounds__(256) void logits_kernel(const float* __restrict__ h,
                                                     const float* __restrict__ a_s,
                                                     const float* __restrict__ a_d,
                                                     float* __restrict__ ls,
                                                     float* __restrict__ ld) {
    const int lane = threadIdx.x & 63;
    const int wid  = threadIdx.x >> 6;
    const int node = blockIdx.x * 4 + wid;
    if (node >= N_NODES) return;
    float ss[HEADS], dd[HEADS];
    #pragma unroll
    for (int hh = 0; hh < HEADS; ++hh) {
        float v = h[(size_t)node * HID + hh * CHAN + lane];
        ss[hh] = v * a_s[hh * CHAN + lane];
        dd[hh] = v * a_d[hh * CHAN + lane];
    }
    #pragma unroll
    for (int o = 32; o > 0; o >>= 1) {
        #pragma unroll
        for (int hh = 0; hh < HEADS; ++hh) {
            ss[hh] += __shfl_down(ss[hh], o);
            dd[hh] += __shfl_down(dd[hh], o);
        }
    }
    if (lane == 0) {
        #pragma unroll
        for (int hh = 0; hh < HEADS; ++hh) {
            ls[node * HEADS + hh] = ss[hh];
            ld[node * HEADS + hh] = dd[hh];
        }
    }
}

// --------------------------------------------------------- GAT aggregation
// wave per dst node; lane owns 4 consecutive channels (float4 gather) and
// its head's weight. Single pass: softmax WITHOUT max-subtraction (logits
// are O(0.1) here; exp-safe; max factor cancels in the normalization —
// rounding-level difference vs reference). Unroll-2 keeps two gathers in
// flight.
__device__ __forceinline__ float leaky(float x) { return fmaxf(x, NEG_SLOPE * x); }

template <bool RELU>
__global__ __launch_bounds__(256) void gat_aggregate(const float* __restrict__ h_in,
                                                     const int* __restrict__ off,
                                                     const int* __restrict__ ssrc,
                                                     const float* __restrict__ ls,
                                                     const float* __restrict__ ld,
                                                     const float* __restrict__ bias,
                                                     float* __restrict__ h_out) {
    const int lane = threadIdx.x & 63;
    const int wid  = threadIdx.x >> 6;
    const int node = blockIdx.x * 4 + wid;
    if (node >= N_NODES) return;
    const int lo = off[node], hi = off[node + 1];
    const int myh = lane >> 4;                 // head of channels 4*lane..4*lane+3
    const float ldv = ld[node * HEADS + myh];

    float4 acc = make_float4(0.f, 0.f, 0.f, 0.f);
    float den = 0.f;
    int e = lo;
    for (; e + 2 <= hi; e += 2) {
        int s0 = ssrc[e];
        int s1 = ssrc[e + 1];
        float l0 = ls[s0 * HEADS + myh];
        float l1 = ls[s1 * HEADS + myh];
        float4 h0 = *(const float4*)(h_in + (size_t)s0 * HID + lane * 4);
        float4 h1 = *(const float4*)(h_in + (size_t)s1 * HID + lane * 4);
        float w0 = __expf(leaky(l0 + ldv));
        float w1 = __expf(leaky(l1 + ldv));
        den += w0 + w1;
        acc.x += w0 * h0.x + w1 * h1.x;
        acc.y += w0 * h0.y + w1 * h1.y;
        acc.z += w0 * h0.z + w1 * h1.z;
        acc.w += w0 * h0.w + w1 * h1.w;
    }
    if (e < hi) {
        int s0 = ssrc[e];
        float w0 = __expf(leaky(ls[s0 * HEADS + myh] + ldv));
        float4 h0 = *(const float4*)(h_in + (size_t)s0 * HID + lane * 4);
        den += w0;
        acc.x += w0 * h0.x; acc.y += w0 * h0.y;
        acc.z += w0 * h0.z; acc.w += w0 * h0.w;
    }
    float inv = 1.f / (den + 1e-16f);
    float4 bv = *(const float4*)(bias + lane * 4);
    float4 o;
    o.x = acc.x * inv + bv.x; o.y = acc.y * inv + bv.y;
    o.z = acc.z * inv + bv.z; o.w = acc.w * inv + bv.w;
    if (RELU) {
        o.x = fmaxf(o.x, 0.f); o.y = fmaxf(o.y, 0.f);
        o.z = fmaxf(o.z, 0.f); o.w = fmaxf(o.w, 0.f);
    }
    *(float4*)(h_out + (size_t)node * HID + lane * 4) = o;
}

// ---------------------------------------------------------------- pooling
__global__ __launch_bounds__(256) void pool_kernel(const float* __restrict__ h,
                                                   const int* __restrict__ batch,
                                                   float* __restrict__ pooled) {
    const int g = blockIdx.x;
    __shared__ int bounds[2];
    if (threadIdx.x < 2) {
        int target = g + threadIdx.x;
        int lo = 0, hi = N_NODES;
        while (lo < hi) {
            int mid = (lo + hi) >> 1;
            if (batch[mid] < target) lo = mid + 1; else hi = mid;
        }
        bounds[threadIdx.x] = lo;
    }
    __syncthreads();
    const int lo = bounds[0], hi = bounds[1];
    const int c = threadIdx.x;
    float s = 0.f;
    for (int i = lo; i < hi; ++i) s += h[(size_t)i * HID + c];
    float cnt = (float)max(hi - lo, 1);
    pooled[(size_t)g * HID + c] = s / cnt;
}

// -------------------------------------------------------------- layernorm
__global__ __launch_bounds__(256) void ln_kernel(const float* __restrict__ z,
                                                 const float* __restrict__ gamma,
                                                 const float* __restrict__ beta,
                                                 float* __restrict__ out) {
    const int row = blockIdx.x;
    const float* zr = z + (size_t)row * NOUT;
    float v[3];
    float s = 0.f, s2 = 0.f;
    #pragma unroll
    for (int i = 0; i < 3; ++i) {
        v[i] = zr[threadIdx.x + i * 256];
        s += v[i];
        s2 += v[i] * v[i];
    }
    #pragma unroll
    for (int o = 32; o > 0; o >>= 1) {
        s  += __shfl_down(s, o);
        s2 += __shfl_down(s2, o);
    }
    __shared__ float red[8];
    const int wid = threadIdx.x >> 6, lane = threadIdx.x & 63;
    if (lane == 0) { red[wid] = s; red[4 + wid] = s2; }
    __syncthreads();
    if (threadIdx.x == 0) {
        float S  = red[0] + red[1] + red[2] + red[3];
        float S2 = red[4] + red[5] + red[6] + red[7];
        float mu  = S / NOUT;
        float var = S2 / NOUT - mu * mu;
        red[0] = mu;
        red[1] = rsqrtf(var + 1e-5f);
    }
    __syncthreads();
    float mu = red[0], rstd = red[1];
    #pragma unroll
    for (int i = 0; i < 3; ++i) {
        int c = threadIdx.x + i * 256;
        out[(size_t)row * NOUT + c] = gamma[c] * (v[i] - mu) * rstd + beta[c];
    }
}

// ------------------------------------------------------------------ launch
extern "C" void kernel_launch(void* const* d_in, const int* in_sizes, int n_in,
                              void* d_out, int out_size, void* d_ws, size_t ws_size,
                              hipStream_t stream) {
    const float* x     = (const float*)d_in[0];
    const int*   ei    = (const int*)d_in[1];
    const int*   batch = (const int*)d_in[2];
    const float* W1    = (const float*)d_in[3];
    const float* a_s1  = (const float*)d_in[4];
    const float* a_d1  = (const float*)d_in[5];
    const float* b1    = (const float*)d_in[6];
    const float* W2    = (const float*)d_in[7];
    const float* a_s2  = (const float*)d_in[8];
    const float* a_d2  = (const float*)d_in[9];
    const float* b2    = (const float*)d_in[10];
    const float* W3    = (const float*)d_in[11];
    const float* a_s3  = (const float*)d_in[12];
    const float* a_d3  = (const float*)d_in[13];
    const float* b3    = (const float*)d_in[14];
    const float* Wm1   = (const float*)d_in[15];
    const float* bm1   = (const float*)d_in[16];
    const float* Wm2   = (const float*)d_in[17];
    const float* bm2   = (const float*)d_in[18];
    const float* gamma = (const float*)d_in[19];
    const float* beta  = (const float*)d_in[20];
    float* out = (float*)d_out;

    char* p = (char*)d_ws;
    auto alloc = [&](size_t bytes) {
        void* r = (void*)p;
        p += (bytes + 255) & ~(size_t)255;
        return r;
    };
    int*   deg    = (int*)  alloc((size_t)N_NODES * 4);
    int*   off    = (int*)  alloc((size_t)(N_NODES + 1) * 4);
    int*   cur    = (int*)  alloc((size_t)N_NODES * 4);
    int*   ssrc   = (int*)  alloc((size_t)N_ETOT * 4);
    float* ls     = (float*)alloc((size_t)N_NODES * HEADS * 4);
    float* ld     = (float*)alloc((size_t)N_NODES * HEADS * 4);
    float* hA     = (float*)alloc((size_t)N_NODES * HID * 4);
    float* hB     = (float*)alloc((size_t)N_NODES * HID * 4);
    float* pooled = (float*)alloc((size_t)NGRAPH * HID * 4);
    float* z1     = (float*)alloc((size_t)NGRAPH * MLP_HID * 4);
    float* z2     = (float*)alloc((size_t)NGRAPH * NOUT * 4);

    // ---- CSR by dst (shared by all layers)
    hipMemsetAsync(deg, 0, (size_t)N_NODES * 4, stream);
    hist_kernel<<<(N_ETOT + 255) / 256, 256, 0, stream>>>(ei, deg);
    scan_kernel<<<1, 1024, 0, stream>>>(deg, off, cur);
    scatter_kernel<<<(N_ETOT + 255) / 256, 256, 0, stream>>>(ei, cur, ssrc);

    const int nodeBlocks = (N_NODES + 3) / 4;
    dim3 gemmN((N_NODES + 127) / 128, HID / 128);   // 391 x 2

    // ---- layer 1
    gemm_kernel<128, 128, 32, 8, 8, false, false><<<gemmN, 256, 0, stream>>>(x, W1, nullptr, hA, N_NODES, HID, F_IN);
    logits_kernel<<<nodeBlocks, 256, 0, stream>>>(hA, a_s1, a_d1, ls, ld);
    gat_aggregate<true><<<nodeBlocks, 256, 0, stream>>>(hA, off, ssrc, ls, ld, b1, hB);

    // ---- layer 2
    gemm_kernel<128, 128, 32, 8, 8, false, false><<<gemmN, 256, 0, stream>>>(hB, W2, nullptr, hA, N_NODES, HID, HID);
    logits_kernel<<<nodeBlocks, 256, 0, stream>>>(hA, a_s2, a_d2, ls, ld);
    gat_aggregate<true><<<nodeBlocks, 256, 0, stream>>>(hA, off, ssrc, ls, ld, b2, hB);

    // ---- layer 3 (no relu)
    gemm_kernel<128, 128, 32, 8, 8, false, false><<<gemmN, 256, 0, stream>>>(hB, W3, nullptr, hA, N_NODES, HID, HID);
    logits_kernel<<<nodeBlocks, 256, 0, stream>>>(hA, a_s3, a_d3, ls, ld);
    gat_aggregate<false><<<nodeBlocks, 256, 0, stream>>>(hA, off, ssrc, ls, ld, b3, hB);

    // ---- pool + MLP + layernorm
    pool_kernel<<<NGRAPH, 256, 0, stream>>>(hB, batch, pooled);
    dim3 gm1(NGRAPH / 64, MLP_HID / 128);           // 16 x 16 = 256 blocks
    gemm_kernel<64, 128, 32, 4, 8, true, true><<<gm1, 256, 0, stream>>>(pooled, Wm1, bm1, z1, NGRAPH, MLP_HID, HID);
    dim3 gm2(NGRAPH / 64, NOUT / 64);               // 16 x 12 = 192 blocks
    gemm_kernel<64, 64, 32, 4, 4, true, false><<<gm2, 256, 0, stream>>>(z1, Wm2, bm2, z2, NGRAPH, NOUT, MLP_HID);
    ln_kernel<<<NGRAPH, 256, 0, stream>>>(z2, gamma, beta, out);
}

// Round 9
// 1089.543 us; speedup vs baseline: 1.1910x; 1.1910x over previous
//
#include <hip/hip_runtime.h>
#include <math.h>

#define N_NODES 50000
#define N_EDGES 800000
#define N_ETOT  850000   /* E + N self-loops */
#define F_IN    32
#define HEADS   4
#define CHAN    64
#define HID     256
#define NGRAPH  1024
#define MLP_HID 2048
#define NOUT    768
#define NEG_SLOPE 0.2f
#define KSPL    4        /* split-K ways for the Wm2 GEMM */

// ---------------------------------------------------------------- CSR build
__global__ __launch_bounds__(256) void hist_kernel(const int* __restrict__ ei,
                                                   int* __restrict__ deg) {
    int e = blockIdx.x * 256 + threadIdx.x;
    if (e >= N_ETOT) return;
    int d = (e < N_EDGES) ? ei[N_EDGES + e] : (e - N_EDGES);
    atomicAdd(&deg[d], 1);
}

__global__ __launch_bounds__(1024) void scan_kernel(const int* __restrict__ deg,
                                                    int* __restrict__ off,
                                                    int* __restrict__ cur) {
    __shared__ int sums[1024];
    const int t = threadIdx.x;
    const int CHK = (N_NODES + 1023) / 1024;   // 49
    int lo = t * CHK;
    int hi = min(lo + CHK, N_NODES);
    int s = 0;
    for (int i = lo; i < hi; ++i) s += deg[i];
    sums[t] = s;
    __syncthreads();
    for (int d = 1; d < 1024; d <<= 1) {
        int v = (t >= d) ? sums[t - d] : 0;
        __syncthreads();
        sums[t] += v;
        __syncthreads();
    }
    int run = sums[t] - s;                     // exclusive prefix
    for (int i = lo; i < hi; ++i) {
        int d0 = deg[i];
        off[i] = run;
        cur[i] = run;
        run += d0;
    }
    if (t == 1023) off[N_NODES] = run;
}

__global__ __launch_bounds__(256) void scatter_kernel(const int* __restrict__ ei,
                                                      int* __restrict__ cur,
                                                      int* __restrict__ ssrc) {
    int e = blockIdx.x * 256 + threadIdx.x;
    if (e >= N_ETOT) return;
    int s, d;
    if (e < N_EDGES) { s = ei[e]; d = ei[N_EDGES + e]; }
    else             { s = e - N_EDGES; d = s; }
    int pos = atomicAdd(&cur[d], 1);
    ssrc[pos] = s;
}

// ---------------------------------------------------------------- fp32 GEMM
// C[M,Nn] = A[M,K] @ B[K,Nn] (+bias)(+relu). BK=16 single-buffer (reverted:
// BK=32+reg-prefetch caused 4-way LDS write conflicts + VGPR bloat, r8).
// As stored TRANSPOSED As[k][m] (pad +4); fragments read as ds_read_b128.
// SPLITK: blockIdx.z selects a K-slice; partials written to C + z*M*Nn.
// lda = row stride of A (= full K of the underlying matrix).
template <int BM, int BN, int TM, int TN, bool BIAS, bool RELU, bool SPLITK>
__global__ __launch_bounds__(256) void gemm_kernel(const float* __restrict__ A,
                                                   const float* __restrict__ B,
                                                   const float* __restrict__ bias,
                                                   float* __restrict__ C,
                                                   int M, int Nn, int K, int lda) {
    __shared__ float As[16][BM + 4];
    __shared__ float Bs[16][BN + 4];
    if (SPLITK) {
        const int z = blockIdx.z;
        A += (size_t)z * K;                    // column offset within lda-stride rows
        B += (size_t)z * K * Nn;
        C += (size_t)z * M * Nn;
    }
    const int t = threadIdx.x;
    const int bm = blockIdx.x * BM;
    const int bn = blockIdx.y * BN;
    constexpr int NTX = BN / TN;               // threads along N
    const int tx = t % NTX;
    const int ty = t / NTX;
    const int row0 = ty * TM;
    const int col0 = tx * TN;
    constexpr int BN4 = BN / 4;
    constexpr int AITER = BM * 4 / 256;        // float4s per thread for A tile
    constexpr int BITER = 16 * BN4 / 256;

    float acc[TM][TN] = {};
    for (int k0 = 0; k0 < K; k0 += 16) {
        #pragma unroll
        for (int it = 0; it < AITER; ++it) {
            int f = t + it * 256;
            int m = f >> 2, kq = (f & 3) << 2;
            int gr = bm + m;
            float4 v = make_float4(0.f, 0.f, 0.f, 0.f);
            if (gr < M) v = *(const float4*)&A[(size_t)gr * lda + k0 + kq];
            As[kq + 0][m] = v.x;
            As[kq + 1][m] = v.y;
            As[kq + 2][m] = v.z;
            As[kq + 3][m] = v.w;
        }
        #pragma unroll
        for (int it = 0; it < BITER; ++it) {
            int f = t + it * 256;
            int k = f / BN4, n = (f % BN4) << 2;
            *(float4*)&Bs[k][n] = *(const float4*)&B[(size_t)(k0 + k) * Nn + bn + n];
        }
        __syncthreads();
        #pragma unroll
        for (int k = 0; k < 16; ++k) {
            float a[TM], b[TN];
            #pragma unroll
            for (int i = 0; i < TM; i += 4)
                *(float4*)&a[i] = *(const float4*)&As[k][row0 + i];
            #pragma unroll
            for (int j = 0; j < TN; j += 4)
                *(float4*)&b[j] = *(const float4*)&Bs[k][col0 + j];
            #pragma unroll
            for (int i = 0; i < TM; ++i)
                #pragma unroll
                for (int j = 0; j < TN; ++j)
                    acc[i][j] += a[i] * b[j];
        }
        __syncthreads();
    }
    #pragma unroll
    for (int i = 0; i < TM; ++i) {
        int r = bm + row0 + i;
        if (r >= M) continue;
        #pragma unroll
        for (int j = 0; j < TN; j += 4) {
            int c = bn + col0 + j;
            float4 v;
            v.x = acc[i][j + 0];
            v.y = acc[i][j + 1];
            v.z = acc[i][j + 2];
            v.w = acc[i][j + 3];
            if (BIAS) {
                const float4 bv = *(const float4*)&bias[c];
                v.x += bv.x; v.y += bv.y; v.z += bv.z; v.w += bv.w;
            }
            if (RELU) {
                v.x = fmaxf(v.x, 0.f); v.y = fmaxf(v.y, 0.f);
                v.z = fmaxf(v.z, 0.f); v.w = fmaxf(v.w, 0.f);
            }
            *(float4*)&C[(size_t)r * Nn + c] = v;
        }
    }
}

// ------------------------------------------------------- attention logits
__global__ __launch_bounds__(256) void logits_kernel(const float* __restrict__ h,
                                                     const float* __restrict__ a_s,
                                                     const float* __restrict__ a_d,
                                                     float* __restrict__ ls,
                                                     float* __restrict__ ld) {
    const int lane = threadIdx.x & 63;
    const int wid  = threadIdx.x >> 6;
    const int node = blockIdx.x * 4 + wid;
    if (node >= N_NODES) return;
    float ss[HEADS], dd[HEADS];
    #pragma unroll
    for (int hh = 0; hh < HEADS; ++hh) {
        float v = h[(size_t)node * HID + hh * CHAN + lane];
        ss[hh] = v * a_s[hh * CHAN + lane];
        dd[hh] = v * a_d[hh * CHAN + lane];
    }
    #pragma unroll
    for (int o = 32; o > 0; o >>= 1) {
        #pragma unroll
        for (int hh = 0; hh < HEADS; ++hh) {
            ss[hh] += __shfl_down(ss[hh], o);
            dd[hh] += __shfl_down(dd[hh], o);
        }
    }
    if (lane == 0) {
        #pragma unroll
        for (int hh = 0; hh < HEADS; ++hh) {
            ls[node * HEADS + hh] = ss[hh];
            ld[node * HEADS + hh] = dd[hh];
        }
    }
}

// --------------------------------------------------------- GAT aggregation
// wave per dst node; lane owns 4 consecutive channels (float4 gather) and
// its head's weight. Single pass, no max-subtraction (logits O(0.1); the
// max factor cancels in normalization — verified absmax-neutral in r8).
__device__ __forceinline__ float leaky(float x) { return fmaxf(x, NEG_SLOPE * x); }

template <bool RELU>
__global__ __launch_bounds__(256) void gat_aggregate(const float* __restrict__ h_in,
                                                     const int* __restrict__ off,
                                                     const int* __restrict__ ssrc,
                                                     const float* __restrict__ ls,
                                                     const float* __restrict__ ld,
                                                     const float* __restrict__ bias,
                                                     float* __restrict__ h_out) {
    const int lane = threadIdx.x & 63;
    const int wid  = threadIdx.x >> 6;
    const int node = blockIdx.x * 4 + wid;
    if (node >= N_NODES) return;
    const int lo = off[node], hi = off[node + 1];
    const int myh = lane >> 4;                 // head of channels 4*lane..4*lane+3
    const float ldv = ld[node * HEADS + myh];

    float4 acc = make_float4(0.f, 0.f, 0.f, 0.f);
    float den = 0.f;
    int e = lo;
    for (; e + 2 <= hi; e += 2) {
        int s0 = ssrc[e];
        int s1 = ssrc[e + 1];
        float l0 = ls[s0 * HEADS + myh];
        float l1 = ls[s1 * HEADS + myh];
        float4 h0 = *(const float4*)(h_in + (size_t)s0 * HID + lane * 4);
        float4 h1 = *(const float4*)(h_in + (size_t)s1 * HID + lane * 4);
        float w0 = __expf(leaky(l0 + ldv));
        float w1 = __expf(leaky(l1 + ldv));
        den += w0 + w1;
        acc.x += w0 * h0.x + w1 * h1.x;
        acc.y += w0 * h0.y + w1 * h1.y;
        acc.z += w0 * h0.z + w1 * h1.z;
        acc.w += w0 * h0.w + w1 * h1.w;
    }
    if (e < hi) {
        int s0 = ssrc[e];
        float w0 = __expf(leaky(ls[s0 * HEADS + myh] + ldv));
        float4 h0 = *(const float4*)(h_in + (size_t)s0 * HID + lane * 4);
        den += w0;
        acc.x += w0 * h0.x; acc.y += w0 * h0.y;
        acc.z += w0 * h0.z; acc.w += w0 * h0.w;
    }
    float inv = 1.f / (den + 1e-16f);
    float4 bv = *(const float4*)(bias + lane * 4);
    float4 o;
    o.x = acc.x * inv + bv.x; o.y = acc.y * inv + bv.y;
    o.z = acc.z * inv + bv.z; o.w = acc.w * inv + bv.w;
    if (RELU) {
        o.x = fmaxf(o.x, 0.f); o.y = fmaxf(o.y, 0.f);
        o.z = fmaxf(o.z, 0.f); o.w = fmaxf(o.w, 0.f);
    }
    *(float4*)(h_out + (size_t)node * HID + lane * 4) = o;
}

// ---------------------------------------------------------------- pooling
__global__ __launch_bounds__(256) void pool_kernel(const float* __restrict__ h,
                                                   const int* __restrict__ batch,
                                                   float* __restrict__ pooled) {
    const int g = blockIdx.x;
    __shared__ int bounds[2];
    if (threadIdx.x < 2) {
        int target = g + threadIdx.x;
        int lo = 0, hi = N_NODES;
        while (lo < hi) {
            int mid = (lo + hi) >> 1;
            if (batch[mid] < target) lo = mid + 1; else hi = mid;
        }
        bounds[threadIdx.x] = lo;
    }
    __syncthreads();
    const int lo = bounds[0], hi = bounds[1];
    const int c = threadIdx.x;
    float s = 0.f;
    for (int i = lo; i < hi; ++i) s += h[(size_t)i * HID + c];
    float cnt = (float)max(hi - lo, 1);
    pooled[(size_t)g * HID + c] = s / cnt;
}

// -------------------------------------------------------------- layernorm
// Reads KSPL split-K partials of z2, sums + bias, then LayerNorm.
__global__ __launch_bounds__(256) void ln_kernel(const float* __restrict__ z2p,
                                                 const float* __restrict__ bm2,
                                                 const float* __restrict__ gamma,
                                                 const float* __restrict__ beta,
                                                 float* __restrict__ out) {
    const int row = blockIdx.x;
    float v[3];
    float s = 0.f, s2 = 0.f;
    #pragma unroll
    for (int i = 0; i < 3; ++i) {
        int c = threadIdx.x + i * 256;
        float a = bm2[c];
        #pragma unroll
        for (int sp = 0; sp < KSPL; ++sp)
            a += z2p[(size_t)sp * NGRAPH * NOUT + (size_t)row * NOUT + c];
        v[i] = a;
        s += a;
        s2 += a * a;
    }
    #pragma unroll
    for (int o = 32; o > 0; o >>= 1) {
        s  += __shfl_down(s, o);
        s2 += __shfl_down(s2, o);
    }
    __shared__ float red[8];
    const int wid = threadIdx.x >> 6, lane = threadIdx.x & 63;
    if (lane == 0) { red[wid] = s; red[4 + wid] = s2; }
    __syncthreads();
    if (threadIdx.x == 0) {
        float S  = red[0] + red[1] + red[2] + red[3];
        float S2 = red[4] + red[5] + red[6] + red[7];
        float mu  = S / NOUT;
        float var = S2 / NOUT - mu * mu;
        red[0] = mu;
        red[1] = rsqrtf(var + 1e-5f);
    }
    __syncthreads();
    float mu = red[0], rstd = red[1];
    #pragma unroll
    for (int i = 0; i < 3; ++i) {
        int c = threadIdx.x + i * 256;
        out[(size_t)row * NOUT + c] = gamma[c] * (v[i] - mu) * rstd + beta[c];
    }
}

// ------------------------------------------------------------------ launch
extern "C" void kernel_launch(void* const* d_in, const int* in_sizes, int n_in,
                              void* d_out, int out_size, void* d_ws, size_t ws_size,
                              hipStream_t stream) {
    const float* x     = (const float*)d_in[0];
    const int*   ei    = (const int*)d_in[1];
    const int*   batch = (const int*)d_in[2];
    const float* W1    = (const float*)d_in[3];
    const float* a_s1  = (const float*)d_in[4];
    const float* a_d1  = (const float*)d_in[5];
    const float* b1    = (const float*)d_in[6];
    const float* W2    = (const float*)d_in[7];
    const float* a_s2  = (const float*)d_in[8];
    const float* a_d2  = (const float*)d_in[9];
    const float* b2    = (const float*)d_in[10];
    const float* W3    = (const float*)d_in[11];
    const float* a_s3  = (const float*)d_in[12];
    const float* a_d3  = (const float*)d_in[13];
    const float* b3    = (const float*)d_in[14];
    const float* Wm1   = (const float*)d_in[15];
    const float* bm1   = (const float*)d_in[16];
    const float* Wm2   = (const float*)d_in[17];
    const float* bm2   = (const float*)d_in[18];
    const float* gamma = (const float*)d_in[19];
    const float* beta  = (const float*)d_in[20];
    float* out = (float*)d_out;

    char* p = (char*)d_ws;
    auto alloc = [&](size_t bytes) {
        void* r = (void*)p;
        p += (bytes + 255) & ~(size_t)255;
        return r;
    };
    int*   deg    = (int*)  alloc((size_t)N_NODES * 4);
    int*   off    = (int*)  alloc((size_t)(N_NODES + 1) * 4);
    int*   cur    = (int*)  alloc((size_t)N_NODES * 4);
    int*   ssrc   = (int*)  alloc((size_t)N_ETOT * 4);
    float* ls     = (float*)alloc((size_t)N_NODES * HEADS * 4);
    float* ld     = (float*)alloc((size_t)N_NODES * HEADS * 4);
    float* hA     = (float*)alloc((size_t)N_NODES * HID * 4);
    float* hB     = (float*)alloc((size_t)N_NODES * HID * 4);
    float* pooled = (float*)alloc((size_t)NGRAPH * HID * 4);
    float* z1     = (float*)alloc((size_t)NGRAPH * MLP_HID * 4);
    float* z2p    = (float*)alloc((size_t)KSPL * NGRAPH * NOUT * 4);

    // ---- CSR by dst (shared by all layers)
    hipMemsetAsync(deg, 0, (size_t)N_NODES * 4, stream);
    hist_kernel<<<(N_ETOT + 255) / 256, 256, 0, stream>>>(ei, deg);
    scan_kernel<<<1, 1024, 0, stream>>>(deg, off, cur);
    scatter_kernel<<<(N_ETOT + 255) / 256, 256, 0, stream>>>(ei, cur, ssrc);

    const int nodeBlocks = (N_NODES + 3) / 4;
    dim3 gemmN((N_NODES + 127) / 128, HID / 128);   // 391 x 2

    // ---- layer 1
    gemm_kernel<128, 128, 8, 8, false, false, false><<<gemmN, 256, 0, stream>>>(x, W1, nullptr, hA, N_NODES, HID, F_IN, F_IN);
    logits_kernel<<<nodeBlocks, 256, 0, stream>>>(hA, a_s1, a_d1, ls, ld);
    gat_aggregate<true><<<nodeBlocks, 256, 0, stream>>>(hA, off, ssrc, ls, ld, b1, hB);

    // ---- layer 2
    gemm_kernel<128, 128, 8, 8, false, false, false><<<gemmN, 256, 0, stream>>>(hB, W2, nullptr, hA, N_NODES, HID, HID, HID);
    logits_kernel<<<nodeBlocks, 256, 0, stream>>>(hA, a_s2, a_d2, ls, ld);
    gat_aggregate<true><<<nodeBlocks, 256, 0, stream>>>(hA, off, ssrc, ls, ld, b2, hB);

    // ---- layer 3 (no relu)
    gemm_kernel<128, 128, 8, 8, false, false, false><<<gemmN, 256, 0, stream>>>(hB, W3, nullptr, hA, N_NODES, HID, HID, HID);
    logits_kernel<<<nodeBlocks, 256, 0, stream>>>(hA, a_s3, a_d3, ls, ld);
    gat_aggregate<false><<<nodeBlocks, 256, 0, stream>>>(hA, off, ssrc, ls, ld, b3, hB);

    // ---- pool + MLP + layernorm
    pool_kernel<<<NGRAPH, 256, 0, stream>>>(hB, batch, pooled);
    dim3 gm1(NGRAPH / 64, MLP_HID / 128);           // 16 x 16 = 256 blocks
    gemm_kernel<64, 128, 4, 8, true, true, false><<<gm1, 256, 0, stream>>>(pooled, Wm1, bm1, z1, NGRAPH, MLP_HID, HID, HID);
    // Wm2: split-K x4 -> 768 blocks; partials summed (+bias) in ln_kernel
    dim3 gm2(NGRAPH / 64, NOUT / 64, KSPL);         // 16 x 12 x 4
    gemm_kernel<64, 64, 4, 4, false, false, true><<<gm2, 256, 0, stream>>>(z1, Wm2, nullptr, z2p, NGRAPH, NOUT, MLP_HID / KSPL, MLP_HID);
    ln_kernel<<<NGRAPH, 256, 0, stream>>>(z2p, bm2, gamma, beta, out);
}

// Round 10
// 886.868 us; speedup vs baseline: 1.4632x; 1.2285x over previous
//
#include <hip/hip_runtime.h>
#include <math.h>

#define N_NODES 50000
#define N_EDGES 800000
#define N_ETOT  850000   /* E + N self-loops */
#define F_IN    32
#define HEADS   4
#define CHAN    64
#define HID     256
#define NGRAPH  1024
#define MLP_HID 2048
#define NOUT    768
#define NEG_SLOPE 0.2f
#define KSPL    4        /* split-K ways for the Wm2 GEMM */

__device__ __forceinline__ unsigned short f2bf(float f) {
    unsigned u = __float_as_uint(f);
    u += 0x7fff + ((u >> 16) & 1);             // round-to-nearest-even
    return (unsigned short)(u >> 16);
}
__device__ __forceinline__ float bf2f(unsigned short s) {
    return __uint_as_float((unsigned)s << 16);
}

// ---------------------------------------------------------------- CSR build
__global__ __launch_bounds__(256) void hist_kernel(const int* __restrict__ ei,
                                                   int* __restrict__ deg) {
    int e = blockIdx.x * 256 + threadIdx.x;
    if (e >= N_ETOT) return;
    int d = (e < N_EDGES) ? ei[N_EDGES + e] : (e - N_EDGES);
    atomicAdd(&deg[d], 1);
}

__global__ __launch_bounds__(1024) void scan_kernel(const int* __restrict__ deg,
                                                    int* __restrict__ off,
                                                    int* __restrict__ cur) {
    __shared__ int sums[1024];
    const int t = threadIdx.x;
    const int CHK = (N_NODES + 1023) / 1024;   // 49
    int lo = t * CHK;
    int hi = min(lo + CHK, N_NODES);
    int s = 0;
    for (int i = lo; i < hi; ++i) s += deg[i];
    sums[t] = s;
    __syncthreads();
    for (int d = 1; d < 1024; d <<= 1) {
        int v = (t >= d) ? sums[t - d] : 0;
        __syncthreads();
        sums[t] += v;
        __syncthreads();
    }
    int run = sums[t] - s;                     // exclusive prefix
    for (int i = lo; i < hi; ++i) {
        int d0 = deg[i];
        off[i] = run;
        cur[i] = run;
        run += d0;
    }
    if (t == 1023) off[N_NODES] = run;
}

__global__ __launch_bounds__(256) void scatter_kernel(const int* __restrict__ ei,
                                                      int* __restrict__ cur,
                                                      int* __restrict__ ssrc) {
    int e = blockIdx.x * 256 + threadIdx.x;
    if (e >= N_ETOT) return;
    int s, d;
    if (e < N_EDGES) { s = ei[e]; d = ei[N_EDGES + e]; }
    else             { s = e - N_EDGES; d = s; }
    int pos = atomicAdd(&cur[d], 1);
    ssrc[pos] = s;
}

// ---------------------------------------------------------------- fp32 GEMM
// C[M,Nn] = A[M,K] @ B[K,Nn] (+bias)(+relu). BK=16 single-buffer.
// As stored TRANSPOSED As[k][m] (pad +4); fragments read as ds_read_b128.
// SPLITK: blockIdx.z selects a K-slice; partials written to C + z*M*Nn.
template <int BM, int BN, int TM, int TN, bool BIAS, bool RELU, bool SPLITK>
__global__ __launch_bounds__(256) void gemm_kernel(const float* __restrict__ A,
                                                   const float* __restrict__ B,
                                                   const float* __restrict__ bias,
                                                   float* __restrict__ C,
                                                   int M, int Nn, int K, int lda) {
    __shared__ float As[16][BM + 4];
    __shared__ float Bs[16][BN + 4];
    if (SPLITK) {
        const int z = blockIdx.z;
        A += (size_t)z * K;
        B += (size_t)z * K * Nn;
        C += (size_t)z * M * Nn;
    }
    const int t = threadIdx.x;
    const int bm = blockIdx.x * BM;
    const int bn = blockIdx.y * BN;
    constexpr int NTX = BN / TN;
    const int tx = t % NTX;
    const int ty = t / NTX;
    const int row0 = ty * TM;
    const int col0 = tx * TN;
    constexpr int BN4 = BN / 4;
    constexpr int AITER = BM * 4 / 256;
    constexpr int BITER = 16 * BN4 / 256;

    float acc[TM][TN] = {};
    for (int k0 = 0; k0 < K; k0 += 16) {
        #pragma unroll
        for (int it = 0; it < AITER; ++it) {
            int f = t + it * 256;
            int m = f >> 2, kq = (f & 3) << 2;
            int gr = bm + m;
            float4 v = make_float4(0.f, 0.f, 0.f, 0.f);
            if (gr < M) v = *(const float4*)&A[(size_t)gr * lda + k0 + kq];
            As[kq + 0][m] = v.x;
            As[kq + 1][m] = v.y;
            As[kq + 2][m] = v.z;
            As[kq + 3][m] = v.w;
        }
        #pragma unroll
        for (int it = 0; it < BITER; ++it) {
            int f = t + it * 256;
            int k = f / BN4, n = (f % BN4) << 2;
            *(float4*)&Bs[k][n] = *(const float4*)&B[(size_t)(k0 + k) * Nn + bn + n];
        }
        __syncthreads();
        #pragma unroll
        for (int k = 0; k < 16; ++k) {
            float a[TM], b[TN];
            #pragma unroll
            for (int i = 0; i < TM; i += 4)
                *(float4*)&a[i] = *(const float4*)&As[k][row0 + i];
            #pragma unroll
            for (int j = 0; j < TN; j += 4)
                *(float4*)&b[j] = *(const float4*)&Bs[k][col0 + j];
            #pragma unroll
            for (int i = 0; i < TM; ++i)
                #pragma unroll
                for (int j = 0; j < TN; ++j)
                    acc[i][j] += a[i] * b[j];
        }
        __syncthreads();
    }
    #pragma unroll
    for (int i = 0; i < TM; ++i) {
        int r = bm + row0 + i;
        if (r >= M) continue;
        #pragma unroll
        for (int j = 0; j < TN; j += 4) {
            int c = bn + col0 + j;
            float4 v;
            v.x = acc[i][j + 0];
            v.y = acc[i][j + 1];
            v.z = acc[i][j + 2];
            v.w = acc[i][j + 3];
            if (BIAS) {
                const float4 bv = *(const float4*)&bias[c];
                v.x += bv.x; v.y += bv.y; v.z += bv.z; v.w += bv.w;
            }
            if (RELU) {
                v.x = fmaxf(v.x, 0.f); v.y = fmaxf(v.y, 0.f);
                v.z = fmaxf(v.z, 0.f); v.w = fmaxf(v.w, 0.f);
            }
            *(float4*)&C[(size_t)r * Nn + c] = v;
        }
    }
}

// ------------------------------------------------------- logits + bf16 pack
// wave per node; lane owns 4 consecutive channels (float4 load). Per-head
// partials reduced within each 16-lane head group. Also emits hb: packed
// bf16 copy of h for the gather-heavy aggregation (halves gather bytes).
__global__ __launch_bounds__(256) void logits_kernel(const float* __restrict__ h,
                                                     const float* __restrict__ a_s,
                                                     const float* __restrict__ a_d,
                                                     float* __restrict__ ls,
                                                     float* __restrict__ ld,
                                                     unsigned short* __restrict__ hb) {
    const int lane = threadIdx.x & 63;
    const int wid  = threadIdx.x >> 6;
    const int node = blockIdx.x * 4 + wid;
    if (node >= N_NODES) return;
    const int myh = lane >> 4;

    float4 v = *(const float4*)&h[(size_t)node * HID + lane * 4];
    // bf16 pack (coalesced 8 B/lane)
    ushort4 q;
    q.x = f2bf(v.x); q.y = f2bf(v.y); q.z = f2bf(v.z); q.w = f2bf(v.w);
    *(ushort4*)&hb[(size_t)node * HID + lane * 4] = q;

    const float4 as4 = *(const float4*)&a_s[lane * 4];
    const float4 ad4 = *(const float4*)&a_d[lane * 4];
    float ss = v.x * as4.x + v.y * as4.y + v.z * as4.z + v.w * as4.w;
    float dd = v.x * ad4.x + v.y * ad4.y + v.z * ad4.z + v.w * ad4.w;
    #pragma unroll
    for (int o = 1; o < 16; o <<= 1) {
        ss += __shfl_xor(ss, o);
        dd += __shfl_xor(dd, o);
    }
    if ((lane & 15) == 0) {
        ls[node * HEADS + myh] = ss;
        ld[node * HEADS + myh] = dd;
    }
}

// --------------------------------------------------------- GAT aggregation
// wave per dst node; lane owns 4 consecutive channels, gathered as bf16
// ushort4 (8 B/lane, 512 B/edge — half the fp32 traffic). fp32 accumulate.
// Single pass, no max-subtraction (max factor cancels; verified r8/r9).
__device__ __forceinline__ float leaky(float x) { return fmaxf(x, NEG_SLOPE * x); }

template <bool RELU>
__global__ __launch_bounds__(256) void gat_aggregate(const unsigned short* __restrict__ hb,
                                                     const int* __restrict__ off,
                                                     const int* __restrict__ ssrc,
                                                     const float* __restrict__ ls,
                                                     const float* __restrict__ ld,
                                                     const float* __restrict__ bias,
                                                     float* __restrict__ h_out) {
    const int lane = threadIdx.x & 63;
    const int wid  = threadIdx.x >> 6;
    const int node = blockIdx.x * 4 + wid;
    if (node >= N_NODES) return;
    const int lo = off[node], hi = off[node + 1];
    const int myh = lane >> 4;
    const float ldv = ld[node * HEADS + myh];

    float4 acc = make_float4(0.f, 0.f, 0.f, 0.f);
    float den = 0.f;
    int e = lo;
    for (; e + 2 <= hi; e += 2) {
        int s0 = ssrc[e];
        int s1 = ssrc[e + 1];
        float l0 = ls[s0 * HEADS + myh];
        float l1 = ls[s1 * HEADS + myh];
        ushort4 q0 = *(const ushort4*)&hb[(size_t)s0 * HID + lane * 4];
        ushort4 q1 = *(const ushort4*)&hb[(size_t)s1 * HID + lane * 4];
        float w0 = __expf(leaky(l0 + ldv));
        float w1 = __expf(leaky(l1 + ldv));
        den += w0 + w1;
        acc.x += w0 * bf2f(q0.x) + w1 * bf2f(q1.x);
        acc.y += w0 * bf2f(q0.y) + w1 * bf2f(q1.y);
        acc.z += w0 * bf2f(q0.z) + w1 * bf2f(q1.z);
        acc.w += w0 * bf2f(q0.w) + w1 * bf2f(q1.w);
    }
    if (e < hi) {
        int s0 = ssrc[e];
        float w0 = __expf(leaky(ls[s0 * HEADS + myh] + ldv));
        ushort4 q0 = *(const ushort4*)&hb[(size_t)s0 * HID + lane * 4];
        den += w0;
        acc.x += w0 * bf2f(q0.x); acc.y += w0 * bf2f(q0.y);
        acc.z += w0 * bf2f(q0.z); acc.w += w0 * bf2f(q0.w);
    }
    float inv = 1.f / (den + 1e-16f);
    float4 bv = *(const float4*)(bias + lane * 4);
    float4 o;
    o.x = acc.x * inv + bv.x; o.y = acc.y * inv + bv.y;
    o.z = acc.z * inv + bv.z; o.w = acc.w * inv + bv.w;
    if (RELU) {
        o.x = fmaxf(o.x, 0.f); o.y = fmaxf(o.y, 0.f);
        o.z = fmaxf(o.z, 0.f); o.w = fmaxf(o.w, 0.f);
    }
    *(float4*)(h_out + (size_t)node * HID + lane * 4) = o;
}

// ---------------------------------------------------------------- pooling
__global__ __launch_bounds__(256) void pool_kernel(const float* __restrict__ h,
                                                   const int* __restrict__ batch,
                                                   float* __restrict__ pooled) {
    const int g = blockIdx.x;
    __shared__ int bounds[2];
    if (threadIdx.x < 2) {
        int target = g + threadIdx.x;
        int lo = 0, hi = N_NODES;
        while (lo < hi) {
            int mid = (lo + hi) >> 1;
            if (batch[mid] < target) lo = mid + 1; else hi = mid;
        }
        bounds[threadIdx.x] = lo;
    }
    __syncthreads();
    const int lo = bounds[0], hi = bounds[1];
    const int c = threadIdx.x;
    float s = 0.f;
    for (int i = lo; i < hi; ++i) s += h[(size_t)i * HID + c];
    float cnt = (float)max(hi - lo, 1);
    pooled[(size_t)g * HID + c] = s / cnt;
}

// -------------------------------------------------------------- layernorm
// Reads KSPL split-K partials of z2, sums + bias, then LayerNorm.
__global__ __launch_bounds__(256) void ln_kernel(const float* __restrict__ z2p,
                                                 const float* __restrict__ bm2,
                                                 const float* __restrict__ gamma,
                                                 const float* __restrict__ beta,
                                                 float* __restrict__ out) {
    const int row = blockIdx.x;
    float v[3];
    float s = 0.f, s2 = 0.f;
    #pragma unroll
    for (int i = 0; i < 3; ++i) {
        int c = threadIdx.x + i * 256;
        float a = bm2[c];
        #pragma unroll
        for (int sp = 0; sp < KSPL; ++sp)
            a += z2p[(size_t)sp * NGRAPH * NOUT + (size_t)row * NOUT + c];
        v[i] = a;
        s += a;
        s2 += a * a;
    }
    #pragma unroll
    for (int o = 32; o > 0; o >>= 1) {
        s  += __shfl_down(s, o);
        s2 += __shfl_down(s2, o);
    }
    __shared__ float red[8];
    const int wid = threadIdx.x >> 6, lane = threadIdx.x & 63;
    if (lane == 0) { red[wid] = s; red[4 + wid] = s2; }
    __syncthreads();
    if (threadIdx.x == 0) {
        float S  = red[0] + red[1] + red[2] + red[3];
        float S2 = red[4] + red[5] + red[6] + red[7];
        float mu  = S / NOUT;
        float var = S2 / NOUT - mu * mu;
        red[0] = mu;
        red[1] = rsqrtf(var + 1e-5f);
    }
    __syncthreads();
    float mu = red[0], rstd = red[1];
    #pragma unroll
    for (int i = 0; i < 3; ++i) {
        int c = threadIdx.x + i * 256;
        out[(size_t)row * NOUT + c] = gamma[c] * (v[i] - mu) * rstd + beta[c];
    }
}

// ------------------------------------------------------------------ launch
extern "C" void kernel_launch(void* const* d_in, const int* in_sizes, int n_in,
                              void* d_out, int out_size, void* d_ws, size_t ws_size,
                              hipStream_t stream) {
    const float* x     = (const float*)d_in[0];
    const int*   ei    = (const int*)d_in[1];
    const int*   batch = (const int*)d_in[2];
    const float* W1    = (const float*)d_in[3];
    const float* a_s1  = (const float*)d_in[4];
    const float* a_d1  = (const float*)d_in[5];
    const float* b1    = (const float*)d_in[6];
    const float* W2    = (const float*)d_in[7];
    const float* a_s2  = (const float*)d_in[8];
    const float* a_d2  = (const float*)d_in[9];
    const float* b2    = (const float*)d_in[10];
    const float* W3    = (const float*)d_in[11];
    const float* a_s3  = (const float*)d_in[12];
    const float* a_d3  = (const float*)d_in[13];
    const float* b3    = (const float*)d_in[14];
    const float* Wm1   = (const float*)d_in[15];
    const float* bm1   = (const float*)d_in[16];
    const float* Wm2   = (const float*)d_in[17];
    const float* bm2   = (const float*)d_in[18];
    const float* gamma = (const float*)d_in[19];
    const float* beta  = (const float*)d_in[20];
    float* out = (float*)d_out;

    char* p = (char*)d_ws;
    auto alloc = [&](size_t bytes) {
        void* r = (void*)p;
        p += (bytes + 255) & ~(size_t)255;
        return r;
    };
    int*   deg    = (int*)  alloc((size_t)N_NODES * 4);
    int*   off    = (int*)  alloc((size_t)(N_NODES + 1) * 4);
    int*   cur    = (int*)  alloc((size_t)N_NODES * 4);
    int*   ssrc   = (int*)  alloc((size_t)N_ETOT * 4);
    float* ls     = (float*)alloc((size_t)N_NODES * HEADS * 4);
    float* ld     = (float*)alloc((size_t)N_NODES * HEADS * 4);
    float* hA     = (float*)alloc((size_t)N_NODES * HID * 4);
    float* hB     = (float*)alloc((size_t)N_NODES * HID * 4);
    unsigned short* hb = (unsigned short*)alloc((size_t)N_NODES * HID * 2);
    float* pooled = (float*)alloc((size_t)NGRAPH * HID * 4);
    float* z1     = (float*)alloc((size_t)NGRAPH * MLP_HID * 4);
    float* z2p    = (float*)alloc((size_t)KSPL * NGRAPH * NOUT * 4);

    // ---- CSR by dst (shared by all layers)
    hipMemsetAsync(deg, 0, (size_t)N_NODES * 4, stream);
    hist_kernel<<<(N_ETOT + 255) / 256, 256, 0, stream>>>(ei, deg);
    scan_kernel<<<1, 1024, 0, stream>>>(deg, off, cur);
    scatter_kernel<<<(N_ETOT + 255) / 256, 256, 0, stream>>>(ei, cur, ssrc);

    const int nodeBlocks = (N_NODES + 3) / 4;
    dim3 gemmN((N_NODES + 127) / 128, HID / 128);   // 391 x 2

    // ---- layer 1
    gemm_kernel<128, 128, 8, 8, false, false, false><<<gemmN, 256, 0, stream>>>(x, W1, nullptr, hA, N_NODES, HID, F_IN, F_IN);
    logits_kernel<<<nodeBlocks, 256, 0, stream>>>(hA, a_s1, a_d1, ls, ld, hb);
    gat_aggregate<true><<<nodeBlocks, 256, 0, stream>>>(hb, off, ssrc, ls, ld, b1, hB);

    // ---- layer 2
    gemm_kernel<128, 128, 8, 8, false, false, false><<<gemmN, 256, 0, stream>>>(hB, W2, nullptr, hA, N_NODES, HID, HID, HID);
    logits_kernel<<<nodeBlocks, 256, 0, stream>>>(hA, a_s2, a_d2, ls, ld, hb);
    gat_aggregate<true><<<nodeBlocks, 256, 0, stream>>>(hb, off, ssrc, ls, ld, b2, hB);

    // ---- layer 3 (no relu)
    gemm_kernel<128, 128, 8, 8, false, false, false><<<gemmN, 256, 0, stream>>>(hB, W3, nullptr, hA, N_NODES, HID, HID, HID);
    logits_kernel<<<nodeBlocks, 256, 0, stream>>>(hA, a_s3, a_d3, ls, ld, hb);
    gat_aggregate<false><<<nodeBlocks, 256, 0, stream>>>(hb, off, ssrc, ls, ld, b3, hB);

    // ---- pool + MLP + layernorm
    pool_kernel<<<NGRAPH, 256, 0, stream>>>(hB, batch, pooled);
    dim3 gm1(NGRAPH / 64, MLP_HID / 128);           // 16 x 16 = 256 blocks
    gemm_kernel<64, 128, 4, 8, true, true, false><<<gm1, 256, 0, stream>>>(pooled, Wm1, bm1, z1, NGRAPH, MLP_HID, HID, HID);
    dim3 gm2(NGRAPH / 64, NOUT / 64, KSPL);         // 16 x 12 x 4
    gemm_kernel<64, 64, 4, 4, false, false, true><<<gm2, 256, 0, stream>>>(z1, Wm2, nullptr, z2p, NGRAPH, NOUT, MLP_HID / KSPL, MLP_HID);
    ln_kernel<<<NGRAPH, 256, 0, stream>>>(z2p, bm2, gamma, beta, out);
}

// Round 13
// 763.630 us; speedup vs baseline: 1.6993x; 1.1614x over previous
//
#include <hip/hip_runtime.h>
#include <math.h>

#define N_NODES 50000
#define N_EDGES 800000
#define N_ETOT  850000   /* E + N self-loops */
#define F_IN    32
#define HEADS   4
#define CHAN    64
#define HID     256
#define NGRAPH  1024
#define MLP_HID 2048
#define NOUT    768
#define NEG_SLOPE 0.2f
#define KSPL    4        /* split-K ways for the Wm2 GEMM */

typedef __attribute__((ext_vector_type(8))) short short8v;   // 8 bf16 (4 VGPRs)
typedef __attribute__((ext_vector_type(4))) float f32x4;     // MFMA accumulator

__device__ __forceinline__ unsigned short f2bf(float f) {
    unsigned u = __float_as_uint(f);
    u += 0x7fff + ((u >> 16) & 1);             // round-to-nearest-even
    return (unsigned short)(u >> 16);
}
__device__ __forceinline__ float bf2f(unsigned short s) {
    return __uint_as_float((unsigned)s << 16);
}

// ---------------------------------------------------------------- CSR build
__global__ __launch_bounds__(256) void hist_kernel(const int* __restrict__ ei,
                                                   int* __restrict__ deg) {
    int e = blockIdx.x * 256 + threadIdx.x;
    if (e >= N_ETOT) return;
    int d = (e < N_EDGES) ? ei[N_EDGES + e] : (e - N_EDGES);
    atomicAdd(&deg[d], 1);
}

__global__ __launch_bounds__(1024) void scan_kernel(const int* __restrict__ deg,
                                                    int* __restrict__ off,
                                                    int* __restrict__ cur) {
    __shared__ int sums[1024];
    const int t = threadIdx.x;
    const int CHK = (N_NODES + 1023) / 1024;   // 49
    int lo = t * CHK;
    int hi = min(lo + CHK, N_NODES);
    int s = 0;
    for (int i = lo; i < hi; ++i) s += deg[i];
    sums[t] = s;
    __syncthreads();
    for (int d = 1; d < 1024; d <<= 1) {
        int v = (t >= d) ? sums[t - d] : 0;
        __syncthreads();
        sums[t] += v;
        __syncthreads();
    }
    int run = sums[t] - s;                     // exclusive prefix
    for (int i = lo; i < hi; ++i) {
        int d0 = deg[i];
        off[i] = run;
        cur[i] = run;
        run += d0;
    }
    if (t == 1023) off[N_NODES] = run;
}

__global__ __launch_bounds__(256) void scatter_kernel(const int* __restrict__ ei,
                                                      int* __restrict__ cur,
                                                      int* __restrict__ ssrc) {
    int e = blockIdx.x * 256 + threadIdx.x;
    if (e >= N_ETOT) return;
    int s, d;
    if (e < N_EDGES) { s = ei[e]; d = ei[N_EDGES + e]; }
    else             { s = e - N_EDGES; d = s; }
    int pos = atomicAdd(&cur[d], 1);
    ssrc[pos] = s;
}

// ----------------------------------------------------- W transpose + cast
// Wt[N][K] bf16 <- W[K][N] fp32 (256x256). Once per weight, amortized over
// all GEMM blocks; makes MFMA LDS staging dense/conflict-free.
__global__ __launch_bounds__(256) void castT_kernel(const float* __restrict__ W,
                                                    unsigned short* __restrict__ Wt) {
    const int r = blockIdx.x;                  // K row
    const int c = threadIdx.x;                 // N col
    Wt[(size_t)c * HID + r] = f2bf(W[(size_t)r * HID + c]);
}

// ------------------------------------------------------ bf16 MFMA GEMM
// C[M,256] = A[M,256] @ B[256,256], B given TRANSPOSED bf16 (Bt[N][K]).
// 64x64 tile, 4 waves; wave w owns rows [16w,16w+16), all 4 col-tiles.
// Asb/Bsb: dense [64][32] bf16 — staging writes and frag reads are 16B.
// mfma_f32_16x16x32_bf16; C: col=lane&15, row=(lane>>4)*4+r (m89-verified).
__global__ __launch_bounds__(256) void gemm_mfma_bt(const float* __restrict__ A,
                                                    const unsigned short* __restrict__ Bt,
                                                    float* __restrict__ C,
                                                    int M) {
    __shared__ unsigned short Asb[64][32];
    __shared__ unsigned short Bsb[64][32];
    const int t = threadIdx.x;
    const int wave = t >> 6;
    const int lane = t & 63;
    const int bm = blockIdx.x * 64;
    const int bn = blockIdx.y * 64;
    const int sr = t >> 2;                     // staging row 0..63
    const int skq = (t & 3) * 8;               // staging k-offset 0/8/16/24
    const int fr = lane & 15;
    const int fq = lane >> 4;

    f32x4 acc[4] = {{0.f,0.f,0.f,0.f},{0.f,0.f,0.f,0.f},
                    {0.f,0.f,0.f,0.f},{0.f,0.f,0.f,0.f}};

    for (int k0 = 0; k0 < HID; k0 += 32) {
        // ---- stage A (fp32 -> bf16), 32B load + 16B LDS write per thread
        {
            const int gr = bm + sr;
            float4 v0 = make_float4(0.f,0.f,0.f,0.f), v1 = v0;
            if (gr < M) {
                v0 = *(const float4*)&A[(size_t)gr * HID + k0 + skq];
                v1 = *(const float4*)&A[(size_t)gr * HID + k0 + skq + 4];
            }
            ushort4 q0, q1;
            q0.x = f2bf(v0.x); q0.y = f2bf(v0.y); q0.z = f2bf(v0.z); q0.w = f2bf(v0.w);
            q1.x = f2bf(v1.x); q1.y = f2bf(v1.y); q1.z = f2bf(v1.z); q1.w = f2bf(v1.w);
            *(ushort4*)&Asb[sr][skq]     = q0;
            *(ushort4*)&Asb[sr][skq + 4] = q1;
        }
        // ---- stage Bt (bf16 direct), one 16B copy per thread
        *(short8v*)&Bsb[sr][skq] =
            *(const short8v*)&Bt[(size_t)(bn + sr) * HID + k0 + skq];
        __syncthreads();

        short8v a = *(short8v*)&Asb[wave * 16 + fr][fq * 8];
        #pragma unroll
        for (int nt = 0; nt < 4; ++nt) {
            short8v b = *(short8v*)&Bsb[nt * 16 + fr][fq * 8];
            acc[nt] = __builtin_amdgcn_mfma_f32_16x16x32_bf16(a, b, acc[nt], 0, 0, 0);
        }
        __syncthreads();
    }

    // ---- C write: row = bm + wave*16 + fq*4 + r, col = bn + nt*16 + fr
    #pragma unroll
    for (int nt = 0; nt < 4; ++nt) {
        #pragma unroll
        for (int r = 0; r < 4; ++r) {
            int row = bm + wave * 16 + fq * 4 + r;
            if (row < M)
                C[(size_t)row * HID + bn + nt * 16 + fr] = acc[nt][r];
        }
    }
}

// ---------------------------------------------------------------- fp32 GEMM
// (layer-1 K=32, Wm1, Wm2-splitK). BK=16 single-buffer, As transposed.
template <int BM, int BN, int TM, int TN, bool BIAS, bool RELU, bool SPLITK>
__global__ __launch_bounds__(256) void gemm_kernel(const float* __restrict__ A,
                                                   const float* __restrict__ B,
                                                   const float* __restrict__ bias,
                                                   float* __restrict__ C,
                                                   int M, int Nn, int K, int lda) {
    __shared__ float As[16][BM + 4];
    __shared__ float Bs[16][BN + 4];
    if (SPLITK) {
        const int z = blockIdx.z;
        A += (size_t)z * K;
        B += (size_t)z * K * Nn;
        C += (size_t)z * M * Nn;
    }
    const int t = threadIdx.x;
    const int bm = blockIdx.x * BM;
    const int bn = blockIdx.y * BN;
    constexpr int NTX = BN / TN;
    const int tx = t % NTX;
    const int ty = t / NTX;
    const int row0 = ty * TM;
    const int col0 = tx * TN;
    constexpr int BN4 = BN / 4;
    constexpr int AITER = BM * 4 / 256;
    constexpr int BITER = 16 * BN4 / 256;

    float acc[TM][TN] = {};
    for (int k0 = 0; k0 < K; k0 += 16) {
        #pragma unroll
        for (int it = 0; it < AITER; ++it) {
            int f = t + it * 256;
            int m = f >> 2, kq = (f & 3) << 2;
            int gr = bm + m;
            float4 v = make_float4(0.f, 0.f, 0.f, 0.f);
            if (gr < M) v = *(const float4*)&A[(size_t)gr * lda + k0 + kq];
            As[kq + 0][m] = v.x;
            As[kq + 1][m] = v.y;
            As[kq + 2][m] = v.z;
            As[kq + 3][m] = v.w;
        }
        #pragma unroll
        for (int it = 0; it < BITER; ++it) {
            int f = t + it * 256;
            int k = f / BN4, n = (f % BN4) << 2;
            *(float4*)&Bs[k][n] = *(const float4*)&B[(size_t)(k0 + k) * Nn + bn + n];
        }
        __syncthreads();
        #pragma unroll
        for (int k = 0; k < 16; ++k) {
            float a[TM], b[TN];
            #pragma unroll
            for (int i = 0; i < TM; i += 4)
                *(float4*)&a[i] = *(const float4*)&As[k][row0 + i];
            #pragma unroll
            for (int j = 0; j < TN; j += 4)
                *(float4*)&b[j] = *(const float4*)&Bs[k][col0 + j];
            #pragma unroll
            for (int i = 0; i < TM; ++i)
                #pragma unroll
                for (int j = 0; j < TN; ++j)
                    acc[i][j] += a[i] * b[j];
        }
        __syncthreads();
    }
    #pragma unroll
    for (int i = 0; i < TM; ++i) {
        int r = bm + row0 + i;
        if (r >= M) continue;
        #pragma unroll
        for (int j = 0; j < TN; j += 4) {
            int c = bn + col0 + j;
            float4 v;
            v.x = acc[i][j + 0];
            v.y = acc[i][j + 1];
            v.z = acc[i][j + 2];
            v.w = acc[i][j + 3];
            if (BIAS) {
                const float4 bv = *(const float4*)&bias[c];
                v.x += bv.x; v.y += bv.y; v.z += bv.z; v.w += bv.w;
            }
            if (RELU) {
                v.x = fmaxf(v.x, 0.f); v.y = fmaxf(v.y, 0.f);
                v.z = fmaxf(v.z, 0.f); v.w = fmaxf(v.w, 0.f);
            }
            *(float4*)&C[(size_t)r * Nn + c] = v;
        }
    }
}

// ------------------------------------------------------- logits + bf16 pack
__global__ __launch_bounds__(256) void logits_kernel(const float* __restrict__ h,
                                                     const float* __restrict__ a_s,
                                                     const float* __restrict__ a_d,
                                                     float* __restrict__ ls,
                                                     float* __restrict__ ld,
                                                     unsigned short* __restrict__ hb) {
    const int lane = threadIdx.x & 63;
    const int wid  = threadIdx.x >> 6;
    const int node = blockIdx.x * 4 + wid;
    if (node >= N_NODES) return;
    const int myh = lane >> 4;

    float4 v = *(const float4*)&h[(size_t)node * HID + lane * 4];
    ushort4 q;
    q.x = f2bf(v.x); q.y = f2bf(v.y); q.z = f2bf(v.z); q.w = f2bf(v.w);
    *(ushort4*)&hb[(size_t)node * HID + lane * 4] = q;

    const float4 as4 = *(const float4*)&a_s[lane * 4];
    const float4 ad4 = *(const float4*)&a_d[lane * 4];
    float ss = v.x * as4.x + v.y * as4.y + v.z * as4.z + v.w * as4.w;
    float dd = v.x * ad4.x + v.y * ad4.y + v.z * ad4.z + v.w * ad4.w;
    #pragma unroll
    for (int o = 1; o < 16; o <<= 1) {
        ss += __shfl_xor(ss, o);
        dd += __shfl_xor(dd, o);
    }
    if ((lane & 15) == 0) {
        ls[node * HEADS + myh] = ss;
        ld[node * HEADS + myh] = dd;
    }
}

// --------------------------------------------------------- GAT aggregation
__device__ __forceinline__ float leaky(float x) { return fmaxf(x, NEG_SLOPE * x); }

template <bool RELU>
__global__ __launch_bounds__(256) void gat_aggregate(const unsigned short* __restrict__ hb,
                                                     const int* __restrict__ off,
                                                     const int* __restrict__ ssrc,
                                                     const float* __restrict__ ls,
                                                     const float* __restrict__ ld,
                                                     const float* __restrict__ bias,
                                                     float* __restrict__ h_out) {
    const int lane = threadIdx.x & 63;
    const int wid  = threadIdx.x >> 6;
    const int node = blockIdx.x * 4 + wid;
    if (node >= N_NODES) return;
    const int lo = off[node], hi = off[node + 1];
    const int myh = lane >> 4;
    const float ldv = ld[node * HEADS + myh];

    float4 acc = make_float4(0.f, 0.f, 0.f, 0.f);
    float den = 0.f;
    int e = lo;
    for (; e + 2 <= hi; e += 2) {
        int s0 = ssrc[e];
        int s1 = ssrc[e + 1];
        float l0 = ls[s0 * HEADS + myh];
        float l1 = ls[s1 * HEADS + myh];
        ushort4 q0 = *(const ushort4*)&hb[(size_t)s0 * HID + lane * 4];
        ushort4 q1 = *(const ushort4*)&hb[(size_t)s1 * HID + lane * 4];
        float w0 = __expf(leaky(l0 + ldv));
        float w1 = __expf(leaky(l1 + ldv));
        den += w0 + w1;
        acc.x += w0 * bf2f(q0.x) + w1 * bf2f(q1.x);
        acc.y += w0 * bf2f(q0.y) + w1 * bf2f(q1.y);
        acc.z += w0 * bf2f(q0.z) + w1 * bf2f(q1.z);
        acc.w += w0 * bf2f(q0.w) + w1 * bf2f(q1.w);
    }
    if (e < hi) {
        int s0 = ssrc[e];
        float w0 = __expf(leaky(ls[s0 * HEADS + myh] + ldv));
        ushort4 q0 = *(const ushort4*)&hb[(size_t)s0 * HID + lane * 4];
        den += w0;
        acc.x += w0 * bf2f(q0.x); acc.y += w0 * bf2f(q0.y);
        acc.z += w0 * bf2f(q0.z); acc.w += w0 * bf2f(q0.w);
    }
    float inv = 1.f / (den + 1e-16f);
    float4 bv = *(const float4*)(bias + lane * 4);
    float4 o;
    o.x = acc.x * inv + bv.x; o.y = acc.y * inv + bv.y;
    o.z = acc.z * inv + bv.z; o.w = acc.w * inv + bv.w;
    if (RELU) {
        o.x = fmaxf(o.x, 0.f); o.y = fmaxf(o.y, 0.f);
        o.z = fmaxf(o.z, 0.f); o.w = fmaxf(o.w, 0.f);
    }
    *(float4*)(h_out + (size_t)node * HID + lane * 4) = o;
}

// ---------------------------------------------------------------- pooling
__global__ __launch_bounds__(256) void pool_kernel(const float* __restrict__ h,
                                                   const int* __restrict__ batch,
                                                   float* __restrict__ pooled) {
    const int g = blockIdx.x;
    __shared__ int bounds[2];
    if (threadIdx.x < 2) {
        int target = g + threadIdx.x;
        int lo = 0, hi = N_NODES;
        while (lo < hi) {
            int mid = (lo + hi) >> 1;
            if (batch[mid] < target) lo = mid + 1; else hi = mid;
        }
        bounds[threadIdx.x] = lo;
    }
    __syncthreads();
    const int lo = bounds[0], hi = bounds[1];
    const int c = threadIdx.x;
    float s = 0.f;
    for (int i = lo; i < hi; ++i) s += h[(size_t)i * HID + c];
    float cnt = (float)max(hi - lo, 1);
    pooled[(size_t)g * HID + c] = s / cnt;
}

// -------------------------------------------------------------- layernorm
__global__ __launch_bounds__(256) void ln_kernel(const float* __restrict__ z2p,
                                                 const float* __restrict__ bm2,
                                                 const float* __restrict__ gamma,
                                                 const float* __restrict__ beta,
                                                 float* __restrict__ out) {
    const int row = blockIdx.x;
    float v[3];
    float s = 0.f, s2 = 0.f;
    #pragma unroll
    for (int i = 0; i < 3; ++i) {
        int c = threadIdx.x + i * 256;
        float a = bm2[c];
        #pragma unroll
        for (int sp = 0; sp < KSPL; ++sp)
            a += z2p[(size_t)sp * NGRAPH * NOUT + (size_t)row * NOUT + c];
        v[i] = a;
        s += a;
        s2 += a * a;
    }
    #pragma unroll
    for (int o = 32; o > 0; o >>= 1) {
        s  += __shfl_down(s, o);
        s2 += __shfl_down(s2, o);
    }
    __shared__ float red[8];
    const int wid = threadIdx.x >> 6, lane = threadIdx.x & 63;
    if (lane == 0) { red[wid] = s; red[4 + wid] = s2; }
    __syncthreads();
    if (threadIdx.x == 0) {
        float S  = red[0] + red[1] + red[2] + red[3];
        float S2 = red[4] + red[5] + red[6] + red[7];
        float mu  = S / NOUT;
        float var = S2 / NOUT - mu * mu;
        red[0] = mu;
        red[1] = rsqrtf(var + 1e-5f);
    }
    __syncthreads();
    float mu = red[0], rstd = red[1];
    #pragma unroll
    for (int i = 0; i < 3; ++i) {
        int c = threadIdx.x + i * 256;
        out[(size_t)row * NOUT + c] = gamma[c] * (v[i] - mu) * rstd + beta[c];
    }
}

// ------------------------------------------------------------------ launch
extern "C" void kernel_launch(void* const* d_in, const int* in_sizes, int n_in,
                              void* d_out, int out_size, void* d_ws, size_t ws_size,
                              hipStream_t stream) {
    const float* x     = (const float*)d_in[0];
    const int*   ei    = (const int*)d_in[1];
    const int*   batch = (const int*)d_in[2];
    const float* W1    = (const float*)d_in[3];
    const float* a_s1  = (const float*)d_in[4];
    const float* a_d1  = (const float*)d_in[5];
    const float* b1    = (const float*)d_in[6];
    const float* W2    = (const float*)d_in[7];
    const float* a_s2  = (const float*)d_in[8];
    const float* a_d2  = (const float*)d_in[9];
    const float* b2    = (const float*)d_in[10];
    const float* W3    = (const float*)d_in[11];
    const float* a_s3  = (const float*)d_in[12];
    const float* a_d3  = (const float*)d_in[13];
    const float* b3    = (const float*)d_in[14];
    const float* Wm1   = (const float*)d_in[15];
    const float* bm1   = (const float*)d_in[16];
    const float* Wm2   = (const float*)d_in[17];
    const float* bm2   = (const float*)d_in[18];
    const float* gamma = (const float*)d_in[19];
    const float* beta  = (const float*)d_in[20];
    float* out = (float*)d_out;

    char* p = (char*)d_ws;
    auto alloc = [&](size_t bytes) {
        void* r = (void*)p;
        p += (bytes + 255) & ~(size_t)255;
        return r;
    };
    int*   deg    = (int*)  alloc((size_t)N_NODES * 4);
    int*   off    = (int*)  alloc((size_t)(N_NODES + 1) * 4);
    int*   cur    = (int*)  alloc((size_t)N_NODES * 4);
    int*   ssrc   = (int*)  alloc((size_t)N_ETOT * 4);
    float* ls     = (float*)alloc((size_t)N_NODES * HEADS * 4);
    float* ld     = (float*)alloc((size_t)N_NODES * HEADS * 4);
    float* hA     = (float*)alloc((size_t)N_NODES * HID * 4);
    float* hB     = (float*)alloc((size_t)N_NODES * HID * 4);
    unsigned short* hb  = (unsigned short*)alloc((size_t)N_NODES * HID * 2);
    unsigned short* W2t = (unsigned short*)alloc((size_t)HID * HID * 2);
    unsigned short* W3t = (unsigned short*)alloc((size_t)HID * HID * 2);
    float* pooled = (float*)alloc((size_t)NGRAPH * HID * 4);
    float* z1     = (float*)alloc((size_t)NGRAPH * MLP_HID * 4);
    float* z2p    = (float*)alloc((size_t)KSPL * NGRAPH * NOUT * 4);

    // ---- CSR by dst + weight transposes (amortized setup)
    hipMemsetAsync(deg, 0, (size_t)N_NODES * 4, stream);
    hist_kernel<<<(N_ETOT + 255) / 256, 256, 0, stream>>>(ei, deg);
    scan_kernel<<<1, 1024, 0, stream>>>(deg, off, cur);
    scatter_kernel<<<(N_ETOT + 255) / 256, 256, 0, stream>>>(ei, cur, ssrc);
    castT_kernel<<<HID, 256, 0, stream>>>(W2, W2t);
    castT_kernel<<<HID, 256, 0, stream>>>(W3, W3t);

    const int nodeBlocks = (N_NODES + 3) / 4;
    dim3 mfmaGrid((N_NODES + 63) / 64, HID / 64);   // 782 x 4

    // ---- layer 1 (K=32: fp32 path)
    dim3 gemmN((N_NODES + 127) / 128, HID / 128);
    gemm_kernel<128, 128, 8, 8, false, false, false><<<gemmN, 256, 0, stream>>>(x, W1, nullptr, hA, N_NODES, HID, F_IN, F_IN);
    logits_kernel<<<nodeBlocks, 256, 0, stream>>>(hA, a_s1, a_d1, ls, ld, hb);
    gat_aggregate<true><<<nodeBlocks, 256, 0, stream>>>(hb, off, ssrc, ls, ld, b1, hB);

    // ---- layer 2 (MFMA bf16)
    gemm_mfma_bt<<<mfmaGrid, 256, 0, stream>>>(hB, W2t, hA, N_NODES);
    logits_kernel<<<nodeBlocks, 256, 0, stream>>>(hA, a_s2, a_d2, ls, ld, hb);
    gat_aggregate<true><<<nodeBlocks, 256, 0, stream>>>(hb, off, ssrc, ls, ld, b2, hB);

    // ---- layer 3 (MFMA bf16, no relu)
    gemm_mfma_bt<<<mfmaGrid, 256, 0, stream>>>(hB, W3t, hA, N_NODES);
    logits_kernel<<<nodeBlocks, 256, 0, stream>>>(hA, a_s3, a_d3, ls, ld, hb);
    gat_aggregate<false><<<nodeBlocks, 256, 0, stream>>>(hb, off, ssrc, ls, ld, b3, hB);

    // ---- pool + MLP + layernorm (fp32 paths)
    pool_kernel<<<NGRAPH, 256, 0, stream>>>(hB, batch, pooled);
    dim3 gm1(NGRAPH / 64, MLP_HID / 128);
    gemm_kernel<64, 128, 4, 8, true, true, false><<<gm1, 256, 0, stream>>>(pooled, Wm1, bm1, z1, NGRAPH, MLP_HID, HID, HID);
    dim3 gm2(NGRAPH / 64, NOUT / 64, KSPL);
    gemm_kernel<64, 64, 4, 4, false, false, true><<<gm2, 256, 0, stream>>>(z1, Wm2, nullptr, z2p, NGRAPH, NOUT, MLP_HID / KSPL, MLP_HID);
    ln_kernel<<<NGRAPH, 256, 0, stream>>>(z2p, bm2, gamma, beta, out);
}

// Round 14
// 659.251 us; speedup vs baseline: 1.9683x; 1.1583x over previous
//
#include <hip/hip_runtime.h>
#include <math.h>

#define N_NODES 50000
#define N_EDGES 800000
#define N_ETOT  850000   /* E + N self-loops */
#define F_IN    32
#define HEADS   4
#define CHAN    64
#define HID     256
#define NGRAPH  1024
#define MLP_HID 2048
#define NOUT    768
#define NEG_SLOPE 0.2f
#define KSPL    4        /* split-K ways for the Wm2 GEMM */
#define NBLK    ((N_NODES + 255) / 256)   /* 196 scan blocks */

typedef __attribute__((ext_vector_type(8))) short short8v;   // 8 bf16 (4 VGPRs)
typedef __attribute__((ext_vector_type(4))) float f32x4;     // MFMA accumulator

__device__ __forceinline__ unsigned short f2bf(float f) {
    unsigned u = __float_as_uint(f);
    u += 0x7fff + ((u >> 16) & 1);             // round-to-nearest-even
    return (unsigned short)(u >> 16);
}
__device__ __forceinline__ float bf2f(unsigned short s) {
    return __uint_as_float((unsigned)s << 16);
}

// ---------------------------------------------------------------- CSR build
__global__ __launch_bounds__(256) void hist_kernel(const int* __restrict__ ei,
                                                   int* __restrict__ deg) {
    int e = blockIdx.x * 256 + threadIdx.x;
    if (e >= N_ETOT) return;
    int d = (e < N_EDGES) ? ei[N_EDGES + e] : (e - N_EDGES);
    atomicAdd(&deg[d], 1);
}

// 3-phase parallel scan (replaces the 110us single-block scan, r13).
// A: per-block sums (coalesced).
__global__ __launch_bounds__(256) void bsum_kernel(const int* __restrict__ deg,
                                                   int* __restrict__ bsum) {
    const int t = threadIdx.x;
    int i = blockIdx.x * 256 + t;
    int v = (i < N_NODES) ? deg[i] : 0;
    #pragma unroll
    for (int o = 32; o > 0; o >>= 1) v += __shfl_down(v, o);
    __shared__ int red[4];
    if ((t & 63) == 0) red[t >> 6] = v;
    __syncthreads();
    if (t == 0) bsum[blockIdx.x] = red[0] + red[1] + red[2] + red[3];
}

// B: scan the 196 block sums (single small block).
__global__ __launch_bounds__(256) void bscan_kernel(const int* __restrict__ bsum,
                                                    int* __restrict__ bpre,
                                                    int* __restrict__ off) {
    __shared__ int s[256];
    const int t = threadIdx.x;
    int v = (t < NBLK) ? bsum[t] : 0;
    s[t] = v;
    __syncthreads();
    for (int d = 1; d < 256; d <<= 1) {
        int u = (t >= d) ? s[t - d] : 0;
        __syncthreads();
        s[t] += u;
        __syncthreads();
    }
    if (t < NBLK) bpre[t] = s[t] - v;          // exclusive block prefix
    if (t == NBLK - 1) off[N_NODES] = s[t];    // total
}

// C: block-local scan + block prefix -> off/cur (coalesced).
__global__ __launch_bounds__(256) void cscan_kernel(const int* __restrict__ deg,
                                                    const int* __restrict__ bpre,
                                                    int* __restrict__ off,
                                                    int* __restrict__ cur) {
    __shared__ int s[256];
    const int t = threadIdx.x;
    const int i = blockIdx.x * 256 + t;
    int v = (i < N_NODES) ? deg[i] : 0;
    s[t] = v;
    __syncthreads();
    for (int d = 1; d < 256; d <<= 1) {
        int u = (t >= d) ? s[t - d] : 0;
        __syncthreads();
        s[t] += u;
        __syncthreads();
    }
    if (i < N_NODES) {
        int pre = bpre[blockIdx.x] + s[t] - v; // exclusive prefix
        off[i] = pre;
        cur[i] = pre;
    }
}

__global__ __launch_bounds__(256) void scatter_kernel(const int* __restrict__ ei,
                                                      int* __restrict__ cur,
                                                      int* __restrict__ ssrc) {
    int e = blockIdx.x * 256 + threadIdx.x;
    if (e >= N_ETOT) return;
    int s, d;
    if (e < N_EDGES) { s = ei[e]; d = ei[N_EDGES + e]; }
    else             { s = e - N_EDGES; d = s; }
    int pos = atomicAdd(&cur[d], 1);
    ssrc[pos] = s;
}

// ----------------------------------------------------- W transpose + cast
__global__ __launch_bounds__(256) void castT_kernel(const float* __restrict__ W,
                                                    unsigned short* __restrict__ Wt) {
    const int r = blockIdx.x;                  // K row
    const int c = threadIdx.x;                 // N col
    Wt[(size_t)c * HID + r] = f2bf(W[(size_t)r * HID + c]);
}

// ------------------------------------------------------ bf16 MFMA GEMM
// C[M,256] = A[M,256] @ B[256,256], B given TRANSPOSED bf16 (Bt[N][K]).
// 64x64 tile, 4 waves; mfma_f32_16x16x32_bf16; C: col=lane&15,
// row=(lane>>4)*4+r (m89-verified).
__global__ __launch_bounds__(256) void gemm_mfma_bt(const float* __restrict__ A,
                                                    const unsigned short* __restrict__ Bt,
                                                    float* __restrict__ C,
                                                    int M) {
    __shared__ unsigned short Asb[64][32];
    __shared__ unsigned short Bsb[64][32];
    const int t = threadIdx.x;
    const int wave = t >> 6;
    const int lane = t & 63;
    const int bm = blockIdx.x * 64;
    const int bn = blockIdx.y * 64;
    const int sr = t >> 2;                     // staging row 0..63
    const int skq = (t & 3) * 8;               // staging k-offset 0/8/16/24
    const int fr = lane & 15;
    const int fq = lane >> 4;

    f32x4 acc[4] = {{0.f,0.f,0.f,0.f},{0.f,0.f,0.f,0.f},
                    {0.f,0.f,0.f,0.f},{0.f,0.f,0.f,0.f}};

    for (int k0 = 0; k0 < HID; k0 += 32) {
        {
            const int gr = bm + sr;
            float4 v0 = make_float4(0.f,0.f,0.f,0.f), v1 = v0;
            if (gr < M) {
                v0 = *(const float4*)&A[(size_t)gr * HID + k0 + skq];
                v1 = *(const float4*)&A[(size_t)gr * HID + k0 + skq + 4];
            }
            ushort4 q0, q1;
            q0.x = f2bf(v0.x); q0.y = f2bf(v0.y); q0.z = f2bf(v0.z); q0.w = f2bf(v0.w);
            q1.x = f2bf(v1.x); q1.y = f2bf(v1.y); q1.z = f2bf(v1.z); q1.w = f2bf(v1.w);
            *(ushort4*)&Asb[sr][skq]     = q0;
            *(ushort4*)&Asb[sr][skq + 4] = q1;
        }
        *(short8v*)&Bsb[sr][skq] =
            *(const short8v*)&Bt[(size_t)(bn + sr) * HID + k0 + skq];
        __syncthreads();

        short8v a = *(short8v*)&Asb[wave * 16 + fr][fq * 8];
        #pragma unroll
        for (int nt = 0; nt < 4; ++nt) {
            short8v b = *(short8v*)&Bsb[nt * 16 + fr][fq * 8];
            acc[nt] = __builtin_amdgcn_mfma_f32_16x16x32_bf16(a, b, acc[nt], 0, 0, 0);
        }
        __syncthreads();
    }

    #pragma unroll
    for (int nt = 0; nt < 4; ++nt) {
        #pragma unroll
        for (int r = 0; r < 4; ++r) {
            int row = bm + wave * 16 + fq * 4 + r;
            if (row < M)
                C[(size_t)row * HID + bn + nt * 16 + fr] = acc[nt][r];
        }
    }
}

// ---------------------------------------------------------------- fp32 GEMM
template <int BM, int BN, int TM, int TN, bool BIAS, bool RELU, bool SPLITK>
__global__ __launch_bounds__(256) void gemm_kernel(const float* __restrict__ A,
                                                   const float* __restrict__ B,
                                                   const float* __restrict__ bias,
                                                   float* __restrict__ C,
                                                   int M, int Nn, int K, int lda) {
    __shared__ float As[16][BM + 4];
    __shared__ float Bs[16][BN + 4];
    if (SPLITK) {
        const int z = blockIdx.z;
        A += (size_t)z * K;
        B += (size_t)z * K * Nn;
        C += (size_t)z * M * Nn;
    }
    const int t = threadIdx.x;
    const int bm = blockIdx.x * BM;
    const int bn = blockIdx.y * BN;
    constexpr int NTX = BN / TN;
    const int tx = t % NTX;
    const int ty = t / NTX;
    const int row0 = ty * TM;
    const int col0 = tx * TN;
    constexpr int BN4 = BN / 4;
    constexpr int AITER = BM * 4 / 256;
    constexpr int BITER = 16 * BN4 / 256;

    float acc[TM][TN] = {};
    for (int k0 = 0; k0 < K; k0 += 16) {
        #pragma unroll
        for (int it = 0; it < AITER; ++it) {
            int f = t + it * 256;
            int m = f >> 2, kq = (f & 3) << 2;
            int gr = bm + m;
            float4 v = make_float4(0.f, 0.f, 0.f, 0.f);
            if (gr < M) v = *(const float4*)&A[(size_t)gr * lda + k0 + kq];
            As[kq + 0][m] = v.x;
            As[kq + 1][m] = v.y;
            As[kq + 2][m] = v.z;
            As[kq + 3][m] = v.w;
        }
        #pragma unroll
        for (int it = 0; it < BITER; ++it) {
            int f = t + it * 256;
            int k = f / BN4, n = (f % BN4) << 2;
            *(float4*)&Bs[k][n] = *(const float4*)&B[(size_t)(k0 + k) * Nn + bn + n];
        }
        __syncthreads();
        #pragma unroll
        for (int k = 0; k < 16; ++k) {
            float a[TM], b[TN];
            #pragma unroll
            for (int i = 0; i < TM; i += 4)
                *(float4*)&a[i] = *(const float4*)&As[k][row0 + i];
            #pragma unroll
            for (int j = 0; j < TN; j += 4)
                *(float4*)&b[j] = *(const float4*)&Bs[k][col0 + j];
            #pragma unroll
            for (int i = 0; i < TM; ++i)
                #pragma unroll
                for (int j = 0; j < TN; ++j)
                    acc[i][j] += a[i] * b[j];
        }
        __syncthreads();
    }
    #pragma unroll
    for (int i = 0; i < TM; ++i) {
        int r = bm + row0 + i;
        if (r >= M) continue;
        #pragma unroll
        for (int j = 0; j < TN; j += 4) {
            int c = bn + col0 + j;
            float4 v;
            v.x = acc[i][j + 0];
            v.y = acc[i][j + 1];
            v.z = acc[i][j + 2];
            v.w = acc[i][j + 3];
            if (BIAS) {
                const float4 bv = *(const float4*)&bias[c];
                v.x += bv.x; v.y += bv.y; v.z += bv.z; v.w += bv.w;
            }
            if (RELU) {
                v.x = fmaxf(v.x, 0.f); v.y = fmaxf(v.y, 0.f);
                v.z = fmaxf(v.z, 0.f); v.w = fmaxf(v.w, 0.f);
            }
            *(float4*)&C[(size_t)r * Nn + c] = v;
        }
    }
}

// ------------------------------------------------------- logits + bf16 pack
__global__ __launch_bounds__(256) void logits_kernel(const float* __restrict__ h,
                                                     const float* __restrict__ a_s,
                                                     const float* __restrict__ a_d,
                                                     float* __restrict__ ls,
                                                     float* __restrict__ ld,
                                                     unsigned short* __restrict__ hb) {
    const int lane = threadIdx.x & 63;
    const int wid  = threadIdx.x >> 6;
    const int node = blockIdx.x * 4 + wid;
    if (node >= N_NODES) return;
    const int myh = lane >> 4;

    float4 v = *(const float4*)&h[(size_t)node * HID + lane * 4];
    ushort4 q;
    q.x = f2bf(v.x); q.y = f2bf(v.y); q.z = f2bf(v.z); q.w = f2bf(v.w);
    *(ushort4*)&hb[(size_t)node * HID + lane * 4] = q;

    const float4 as4 = *(const float4*)&a_s[lane * 4];
    const float4 ad4 = *(const float4*)&a_d[lane * 4];
    float ss = v.x * as4.x + v.y * as4.y + v.z * as4.z + v.w * as4.w;
    float dd = v.x * ad4.x + v.y * ad4.y + v.z * ad4.z + v.w * ad4.w;
    #pragma unroll
    for (int o = 1; o < 16; o <<= 1) {
        ss += __shfl_xor(ss, o);
        dd += __shfl_xor(dd, o);
    }
    if ((lane & 15) == 0) {
        ls[node * HEADS + myh] = ss;
        ld[node * HEADS + myh] = dd;
    }
}

// --------------------------------------------------------- GAT aggregation
__device__ __forceinline__ float leaky(float x) { return fmaxf(x, NEG_SLOPE * x); }

template <bool RELU>
__global__ __launch_bounds__(256) void gat_aggregate(const unsigned short* __restrict__ hb,
                                                     const int* __restrict__ off,
                                                     const int* __restrict__ ssrc,
                                                     const float* __restrict__ ls,
                                                     const float* __restrict__ ld,
                                                     const float* __restrict__ bias,
                                                     float* __restrict__ h_out) {
    const int lane = threadIdx.x & 63;
    const int wid  = threadIdx.x >> 6;
    const int node = blockIdx.x * 4 + wid;
    if (node >= N_NODES) return;
    const int lo = off[node], hi = off[node + 1];
    const int myh = lane >> 4;
    const float ldv = ld[node * HEADS + myh];

    float4 acc = make_float4(0.f, 0.f, 0.f, 0.f);
    float den = 0.f;
    int e = lo;
    for (; e + 2 <= hi; e += 2) {
        int s0 = ssrc[e];
        int s1 = ssrc[e + 1];
        float l0 = ls[s0 * HEADS + myh];
        float l1 = ls[s1 * HEADS + myh];
        ushort4 q0 = *(const ushort4*)&hb[(size_t)s0 * HID + lane * 4];
        ushort4 q1 = *(const ushort4*)&hb[(size_t)s1 * HID + lane * 4];
        float w0 = __expf(leaky(l0 + ldv));
        float w1 = __expf(leaky(l1 + ldv));
        den += w0 + w1;
        acc.x += w0 * bf2f(q0.x) + w1 * bf2f(q1.x);
        acc.y += w0 * bf2f(q0.y) + w1 * bf2f(q1.y);
        acc.z += w0 * bf2f(q0.z) + w1 * bf2f(q1.z);
        acc.w += w0 * bf2f(q0.w) + w1 * bf2f(q1.w);
    }
    if (e < hi) {
        int s0 = ssrc[e];
        float w0 = __expf(leaky(ls[s0 * HEADS + myh] + ldv));
        ushort4 q0 = *(const ushort4*)&hb[(size_t)s0 * HID + lane * 4];
        den += w0;
        acc.x += w0 * bf2f(q0.x); acc.y += w0 * bf2f(q0.y);
        acc.z += w0 * bf2f(q0.z); acc.w += w0 * bf2f(q0.w);
    }
    float inv = 1.f / (den + 1e-16f);
    float4 bv = *(const float4*)(bias + lane * 4);
    float4 o;
    o.x = acc.x * inv + bv.x; o.y = acc.y * inv + bv.y;
    o.z = acc.z * inv + bv.z; o.w = acc.w * inv + bv.w;
    if (RELU) {
        o.x = fmaxf(o.x, 0.f); o.y = fmaxf(o.y, 0.f);
        o.z = fmaxf(o.z, 0.f); o.w = fmaxf(o.w, 0.f);
    }
    *(float4*)(h_out + (size_t)node * HID + lane * 4) = o;
}

// ---------------------------------------------------------------- pooling
__global__ __launch_bounds__(256) void pool_kernel(const float* __restrict__ h,
                                                   const int* __restrict__ batch,
                                                   float* __restrict__ pooled) {
    const int g = blockIdx.x;
    __shared__ int bounds[2];
    if (threadIdx.x < 2) {
        int target = g + threadIdx.x;
        int lo = 0, hi = N_NODES;
        while (lo < hi) {
            int mid = (lo + hi) >> 1;
            if (batch[mid] < target) lo = mid + 1; else hi = mid;
        }
        bounds[threadIdx.x] = lo;
    }
    __syncthreads();
    const int lo = bounds[0], hi = bounds[1];
    const int c = threadIdx.x;
    float s = 0.f;
    for (int i = lo; i < hi; ++i) s += h[(size_t)i * HID + c];
    float cnt = (float)max(hi - lo, 1);
    pooled[(size_t)g * HID + c] = s / cnt;
}

// -------------------------------------------------------------- layernorm
__global__ __launch_bounds__(256) void ln_kernel(const float* __restrict__ z2p,
                                                 const float* __restrict__ bm2,
                                                 const float* __restrict__ gamma,
                                                 const float* __restrict__ beta,
                                                 float* __restrict__ out) {
    const int row = blockIdx.x;
    float v[3];
    float s = 0.f, s2 = 0.f;
    #pragma unroll
    for (int i = 0; i < 3; ++i) {
        int c = threadIdx.x + i * 256;
        float a = bm2[c];
        #pragma unroll
        for (int sp = 0; sp < KSPL; ++sp)
            a += z2p[(size_t)sp * NGRAPH * NOUT + (size_t)row * NOUT + c];
        v[i] = a;
        s += a;
        s2 += a * a;
    }
    #pragma unroll
    for (int o = 32; o > 0; o >>= 1) {
        s  += __shfl_down(s, o);
        s2 += __shfl_down(s2, o);
    }
    __shared__ float red[8];
    const int wid = threadIdx.x >> 6, lane = threadIdx.x & 63;
    if (lane == 0) { red[wid] = s; red[4 + wid] = s2; }
    __syncthreads();
    if (threadIdx.x == 0) {
        float S  = red[0] + red[1] + red[2] + red[3];
        float S2 = red[4] + red[5] + red[6] + red[7];
        float mu  = S / NOUT;
        float var = S2 / NOUT - mu * mu;
        red[0] = mu;
        red[1] = rsqrtf(var + 1e-5f);
    }
    __syncthreads();
    float mu = red[0], rstd = red[1];
    #pragma unroll
    for (int i = 0; i < 3; ++i) {
        int c = threadIdx.x + i * 256;
        out[(size_t)row * NOUT + c] = gamma[c] * (v[i] - mu) * rstd + beta[c];
    }
}

// ------------------------------------------------------------------ launch
extern "C" void kernel_launch(void* const* d_in, const int* in_sizes, int n_in,
                              void* d_out, int out_size, void* d_ws, size_t ws_size,
                              hipStream_t stream) {
    const float* x     = (const float*)d_in[0];
    const int*   ei    = (const int*)d_in[1];
    const int*   batch = (const int*)d_in[2];
    const float* W1    = (const float*)d_in[3];
    const float* a_s1  = (const float*)d_in[4];
    const float* a_d1  = (const float*)d_in[5];
    const float* b1    = (const float*)d_in[6];
    const float* W2    = (const float*)d_in[7];
    const float* a_s2  = (const float*)d_in[8];
    const float* a_d2  = (const float*)d_in[9];
    const float* b2    = (const float*)d_in[10];
    const float* W3    = (const float*)d_in[11];
    const float* a_s3  = (const float*)d_in[12];
    const float* a_d3  = (const float*)d_in[13];
    const float* b3    = (const float*)d_in[14];
    const float* Wm1   = (const float*)d_in[15];
    const float* bm1   = (const float*)d_in[16];
    const float* Wm2   = (const float*)d_in[17];
    const float* bm2   = (const float*)d_in[18];
    const float* gamma = (const float*)d_in[19];
    const float* beta  = (const float*)d_in[20];
    float* out = (float*)d_out;

    char* p = (char*)d_ws;
    auto alloc = [&](size_t bytes) {
        void* r = (void*)p;
        p += (bytes + 255) & ~(size_t)255;
        return r;
    };
    int*   deg    = (int*)  alloc((size_t)N_NODES * 4);
    int*   off    = (int*)  alloc((size_t)(N_NODES + 1) * 4);
    int*   cur    = (int*)  alloc((size_t)N_NODES * 4);
    int*   ssrc   = (int*)  alloc((size_t)N_ETOT * 4);
    int*   bsum   = (int*)  alloc((size_t)256 * 4);
    int*   bpre   = (int*)  alloc((size_t)256 * 4);
    float* ls     = (float*)alloc((size_t)N_NODES * HEADS * 4);
    float* ld     = (float*)alloc((size_t)N_NODES * HEADS * 4);
    float* hA     = (float*)alloc((size_t)N_NODES * HID * 4);
    float* hB     = (float*)alloc((size_t)N_NODES * HID * 4);
    unsigned short* hb  = (unsigned short*)alloc((size_t)N_NODES * HID * 2);
    unsigned short* W2t = (unsigned short*)alloc((size_t)HID * HID * 2);
    unsigned short* W3t = (unsigned short*)alloc((size_t)HID * HID * 2);
    float* pooled = (float*)alloc((size_t)NGRAPH * HID * 4);
    float* z1     = (float*)alloc((size_t)NGRAPH * MLP_HID * 4);
    float* z2p    = (float*)alloc((size_t)KSPL * NGRAPH * NOUT * 4);

    // ---- CSR by dst (3-phase parallel scan) + weight transposes
    hipMemsetAsync(deg, 0, (size_t)N_NODES * 4, stream);
    hist_kernel<<<(N_ETOT + 255) / 256, 256, 0, stream>>>(ei, deg);
    bsum_kernel<<<NBLK, 256, 0, stream>>>(deg, bsum);
    bscan_kernel<<<1, 256, 0, stream>>>(bsum, bpre, off);
    cscan_kernel<<<NBLK, 256, 0, stream>>>(deg, bpre, off, cur);
    scatter_kernel<<<(N_ETOT + 255) / 256, 256, 0, stream>>>(ei, cur, ssrc);
    castT_kernel<<<HID, 256, 0, stream>>>(W2, W2t);
    castT_kernel<<<HID, 256, 0, stream>>>(W3, W3t);

    const int nodeBlocks = (N_NODES + 3) / 4;
    dim3 mfmaGrid((N_NODES + 63) / 64, HID / 64);   // 782 x 4

    // ---- layer 1 (K=32: fp32 path)
    dim3 gemmN((N_NODES + 127) / 128, HID / 128);
    gemm_kernel<128, 128, 8, 8, false, false, false><<<gemmN, 256, 0, stream>>>(x, W1, nullptr, hA, N_NODES, HID, F_IN, F_IN);
    logits_kernel<<<nodeBlocks, 256, 0, stream>>>(hA, a_s1, a_d1, ls, ld, hb);
    gat_aggregate<true><<<nodeBlocks, 256, 0, stream>>>(hb, off, ssrc, ls, ld, b1, hB);

    // ---- layer 2 (MFMA bf16)
    gemm_mfma_bt<<<mfmaGrid, 256, 0, stream>>>(hB, W2t, hA, N_NODES);
    logits_kernel<<<nodeBlocks, 256, 0, stream>>>(hA, a_s2, a_d2, ls, ld, hb);
    gat_aggregate<true><<<nodeBlocks, 256, 0, stream>>>(hb, off, ssrc, ls, ld, b2, hB);

    // ---- layer 3 (MFMA bf16, no relu)
    gemm_mfma_bt<<<mfmaGrid, 256, 0, stream>>>(hB, W3t, hA, N_NODES);
    logits_kernel<<<nodeBlocks, 256, 0, stream>>>(hA, a_s3, a_d3, ls, ld, hb);
    gat_aggregate<false><<<nodeBlocks, 256, 0, stream>>>(hb, off, ssrc, ls, ld, b3, hB);

    // ---- pool + MLP + layernorm (fp32 paths)
    pool_kernel<<<NGRAPH, 256, 0, stream>>>(hB, batch, pooled);
    dim3 gm1(NGRAPH / 64, MLP_HID / 128);
    gemm_kernel<64, 128, 4, 8, true, true, false><<<gm1, 256, 0, stream>>>(pooled, Wm1, bm1, z1, NGRAPH, MLP_HID, HID, HID);
    dim3 gm2(NGRAPH / 64, NOUT / 64, KSPL);
    gemm_kernel<64, 64, 4, 4, false, false, true><<<gm2, 256, 0, stream>>>(z1, Wm2, nullptr, z2p, NGRAPH, NOUT, MLP_HID / KSPL, MLP_HID);
    ln_kernel<<<NGRAPH, 256, 0, stream>>>(z2p, bm2, gamma, beta, out);
}

// Round 15
// 627.755 us; speedup vs baseline: 2.0671x; 1.0502x over previous
//
#include <hip/hip_runtime.h>
#include <math.h>

#define N_NODES 50000
#define N_EDGES 800000
#define N_ETOT  850000   /* E + N self-loops */
#define F_IN    32
#define HEADS   4
#define CHAN    64
#define HID     256
#define NGRAPH  1024
#define MLP_HID 2048
#define NOUT    768
#define NEG_SLOPE 0.2f
#define KSPL    4        /* split-K ways for the Wm2 GEMM */
#define NBLK    ((N_NODES + 255) / 256)   /* 196 scan blocks */

typedef __attribute__((ext_vector_type(8))) short short8v;   // 8 bf16 (4 VGPRs)
typedef __attribute__((ext_vector_type(4))) float f32x4;     // MFMA accumulator

__device__ __forceinline__ unsigned short f2bf(float f) {
    unsigned u = __float_as_uint(f);
    u += 0x7fff + ((u >> 16) & 1);             // round-to-nearest-even
    return (unsigned short)(u >> 16);
}
__device__ __forceinline__ float bf2f(unsigned short s) {
    return __uint_as_float((unsigned)s << 16);
}

// ---------------------------------------------------------------- CSR build
__global__ __launch_bounds__(256) void hist_kernel(const int* __restrict__ ei,
                                                   int* __restrict__ deg) {
    int e = blockIdx.x * 256 + threadIdx.x;
    if (e >= N_ETOT) return;
    int d = (e < N_EDGES) ? ei[N_EDGES + e] : (e - N_EDGES);
    atomicAdd(&deg[d], 1);
}

// 3-phase parallel scan (r14: replaced 110us single-block scan).
__global__ __launch_bounds__(256) void bsum_kernel(const int* __restrict__ deg,
                                                   int* __restrict__ bsum) {
    const int t = threadIdx.x;
    int i = blockIdx.x * 256 + t;
    int v = (i < N_NODES) ? deg[i] : 0;
    #pragma unroll
    for (int o = 32; o > 0; o >>= 1) v += __shfl_down(v, o);
    __shared__ int red[4];
    if ((t & 63) == 0) red[t >> 6] = v;
    __syncthreads();
    if (t == 0) bsum[blockIdx.x] = red[0] + red[1] + red[2] + red[3];
}

__global__ __launch_bounds__(256) void bscan_kernel(const int* __restrict__ bsum,
                                                    int* __restrict__ bpre,
                                                    int* __restrict__ off) {
    __shared__ int s[256];
    const int t = threadIdx.x;
    int v = (t < NBLK) ? bsum[t] : 0;
    s[t] = v;
    __syncthreads();
    for (int d = 1; d < 256; d <<= 1) {
        int u = (t >= d) ? s[t - d] : 0;
        __syncthreads();
        s[t] += u;
        __syncthreads();
    }
    if (t < NBLK) bpre[t] = s[t] - v;          // exclusive block prefix
    if (t == NBLK - 1) off[N_NODES] = s[t];    // total
}

__global__ __launch_bounds__(256) void cscan_kernel(const int* __restrict__ deg,
                                                    const int* __restrict__ bpre,
                                                    int* __restrict__ off,
                                                    int* __restrict__ cur) {
    __shared__ int s[256];
    const int t = threadIdx.x;
    const int i = blockIdx.x * 256 + t;
    int v = (i < N_NODES) ? deg[i] : 0;
    s[t] = v;
    __syncthreads();
    for (int d = 1; d < 256; d <<= 1) {
        int u = (t >= d) ? s[t - d] : 0;
        __syncthreads();
        s[t] += u;
        __syncthreads();
    }
    if (i < N_NODES) {
        int pre = bpre[blockIdx.x] + s[t] - v;
        off[i] = pre;
        cur[i] = pre;
    }
}

__global__ __launch_bounds__(256) void scatter_kernel(const int* __restrict__ ei,
                                                      int* __restrict__ cur,
                                                      int* __restrict__ ssrc) {
    int e = blockIdx.x * 256 + threadIdx.x;
    if (e >= N_ETOT) return;
    int s, d;
    if (e < N_EDGES) { s = ei[e]; d = ei[N_EDGES + e]; }
    else             { s = e - N_EDGES; d = s; }
    int pos = atomicAdd(&cur[d], 1);
    ssrc[pos] = s;
}

// ----------------------------------------------------- W transpose + cast
__global__ __launch_bounds__(256) void castT_kernel(const float* __restrict__ W,
                                                    unsigned short* __restrict__ Wt) {
    const int r = blockIdx.x;                  // K row
    const int c = threadIdx.x;                 // N col
    Wt[(size_t)c * HID + r] = f2bf(W[(size_t)r * HID + c]);
}

// ------------------------------------------- bf16 MFMA GEMM + fused logits
// hb[M,256](bf16) = A[M,256] @ B (Bt[N][K] bf16); since a bn-tile (64 cols)
// is exactly one head, the epilogue also computes ls/ld for that head:
// partial over own fr column, 16-lane shfl_xor reduce within fq group.
// Eliminates the fp32 C round-trip (51MB write + 51MB read) and the
// standalone logits pass for layers 2/3.
__global__ __launch_bounds__(256) void gemm_mfma_fused(const float* __restrict__ A,
                                                       const unsigned short* __restrict__ Bt,
                                                       const float* __restrict__ a_s,
                                                       const float* __restrict__ a_d,
                                                       unsigned short* __restrict__ hb,
                                                       float* __restrict__ ls,
                                                       float* __restrict__ ld,
                                                       int M) {
    __shared__ unsigned short Asb[64][32];
    __shared__ unsigned short Bsb[64][32];
    const int t = threadIdx.x;
    const int wave = t >> 6;
    const int lane = t & 63;
    const int bm = blockIdx.x * 64;
    const int head = blockIdx.y;               // bn = head * 64
    const int bn = head * 64;
    const int sr = t >> 2;
    const int skq = (t & 3) * 8;
    const int fr = lane & 15;
    const int fq = lane >> 4;

    f32x4 acc[4] = {{0.f,0.f,0.f,0.f},{0.f,0.f,0.f,0.f},
                    {0.f,0.f,0.f,0.f},{0.f,0.f,0.f,0.f}};

    for (int k0 = 0; k0 < HID; k0 += 32) {
        {
            const int gr = bm + sr;
            float4 v0 = make_float4(0.f,0.f,0.f,0.f), v1 = v0;
            if (gr < M) {
                v0 = *(const float4*)&A[(size_t)gr * HID + k0 + skq];
                v1 = *(const float4*)&A[(size_t)gr * HID + k0 + skq + 4];
            }
            ushort4 q0, q1;
            q0.x = f2bf(v0.x); q0.y = f2bf(v0.y); q0.z = f2bf(v0.z); q0.w = f2bf(v0.w);
            q1.x = f2bf(v1.x); q1.y = f2bf(v1.y); q1.z = f2bf(v1.z); q1.w = f2bf(v1.w);
            *(ushort4*)&Asb[sr][skq]     = q0;
            *(ushort4*)&Asb[sr][skq + 4] = q1;
        }
        *(short8v*)&Bsb[sr][skq] =
            *(const short8v*)&Bt[(size_t)(bn + sr) * HID + k0 + skq];
        __syncthreads();

        short8v a = *(short8v*)&Asb[wave * 16 + fr][fq * 8];
        #pragma unroll
        for (int nt = 0; nt < 4; ++nt) {
            short8v b = *(short8v*)&Bsb[nt * 16 + fr][fq * 8];
            acc[nt] = __builtin_amdgcn_mfma_f32_16x16x32_bf16(a, b, acc[nt], 0, 0, 0);
        }
        __syncthreads();
    }

    // ---- fused epilogue: hb (bf16) + per-head logits
    float pS[4] = {0.f, 0.f, 0.f, 0.f};
    float pD[4] = {0.f, 0.f, 0.f, 0.f};
    #pragma unroll
    for (int nt = 0; nt < 4; ++nt) {
        const float asv = a_s[head * CHAN + nt * 16 + fr];
        const float adv = a_d[head * CHAN + nt * 16 + fr];
        #pragma unroll
        for (int r = 0; r < 4; ++r) {
            const float c = acc[nt][r];
            pS[r] += c * asv;
            pD[r] += c * adv;
            int row = bm + wave * 16 + fq * 4 + r;
            if (row < M)
                hb[(size_t)row * HID + bn + nt * 16 + fr] = f2bf(c);
        }
    }
    #pragma unroll
    for (int o = 1; o < 16; o <<= 1) {
        #pragma unroll
        for (int r = 0; r < 4; ++r) {
            pS[r] += __shfl_xor(pS[r], o);
            pD[r] += __shfl_xor(pD[r], o);
        }
    }
    if (fr == 0) {
        #pragma unroll
        for (int r = 0; r < 4; ++r) {
            int row = bm + wave * 16 + fq * 4 + r;
            if (row < M) {
                ls[row * HEADS + head] = pS[r];
                ld[row * HEADS + head] = pD[r];
            }
        }
    }
}

// ---------------------------------------------------------------- fp32 GEMM
template <int BM, int BN, int TM, int TN, bool BIAS, bool RELU, bool SPLITK>
__global__ __launch_bounds__(256) void gemm_kernel(const float* __restrict__ A,
                                                   const float* __restrict__ B,
                                                   const float* __restrict__ bias,
                                                   float* __restrict__ C,
                                                   int M, int Nn, int K, int lda) {
    __shared__ float As[16][BM + 4];
    __shared__ float Bs[16][BN + 4];
    if (SPLITK) {
        const int z = blockIdx.z;
        A += (size_t)z * K;
        B += (size_t)z * K * Nn;
        C += (size_t)z * M * Nn;
    }
    const int t = threadIdx.x;
    const int bm = blockIdx.x * BM;
    const int bn = blockIdx.y * BN;
    constexpr int NTX = BN / TN;
    const int tx = t % NTX;
    const int ty = t / NTX;
    const int row0 = ty * TM;
    const int col0 = tx * TN;
    constexpr int BN4 = BN / 4;
    constexpr int AITER = BM * 4 / 256;
    constexpr int BITER = 16 * BN4 / 256;

    float acc[TM][TN] = {};
    for (int k0 = 0; k0 < K; k0 += 16) {
        #pragma unroll
        for (int it = 0; it < AITER; ++it) {
            int f = t + it * 256;
            int m = f >> 2, kq = (f & 3) << 2;
            int gr = bm + m;
            float4 v = make_float4(0.f, 0.f, 0.f, 0.f);
            if (gr < M) v = *(const float4*)&A[(size_t)gr * lda + k0 + kq];
            As[kq + 0][m] = v.x;
            As[kq + 1][m] = v.y;
            As[kq + 2][m] = v.z;
            As[kq + 3][m] = v.w;
        }
        #pragma unroll
        for (int it = 0; it < BITER; ++it) {
            int f = t + it * 256;
            int k = f / BN4, n = (f % BN4) << 2;
            *(float4*)&Bs[k][n] = *(const float4*)&B[(size_t)(k0 + k) * Nn + bn + n];
        }
        __syncthreads();
        #pragma unroll
        for (int k = 0; k < 16; ++k) {
            float a[TM], b[TN];
            #pragma unroll
            for (int i = 0; i < TM; i += 4)
                *(float4*)&a[i] = *(const float4*)&As[k][row0 + i];
            #pragma unroll
            for (int j = 0; j < TN; j += 4)
                *(float4*)&b[j] = *(const float4*)&Bs[k][col0 + j];
            #pragma unroll
            for (int i = 0; i < TM; ++i)
                #pragma unroll
                for (int j = 0; j < TN; ++j)
                    acc[i][j] += a[i] * b[j];
        }
        __syncthreads();
    }
    #pragma unroll
    for (int i = 0; i < TM; ++i) {
        int r = bm + row0 + i;
        if (r >= M) continue;
        #pragma unroll
        for (int j = 0; j < TN; j += 4) {
            int c = bn + col0 + j;
            float4 v;
            v.x = acc[i][j + 0];
            v.y = acc[i][j + 1];
            v.z = acc[i][j + 2];
            v.w = acc[i][j + 3];
            if (BIAS) {
                const float4 bv = *(const float4*)&bias[c];
                v.x += bv.x; v.y += bv.y; v.z += bv.z; v.w += bv.w;
            }
            if (RELU) {
                v.x = fmaxf(v.x, 0.f); v.y = fmaxf(v.y, 0.f);
                v.z = fmaxf(v.z, 0.f); v.w = fmaxf(v.w, 0.f);
            }
            *(float4*)&C[(size_t)r * Nn + c] = v;
        }
    }
}

// ------------------------------------------------------- logits + bf16 pack
// (layer 1 only; layers 2/3 are fused into the MFMA GEMM epilogue)
__global__ __launch_bounds__(256) void logits_kernel(const float* __restrict__ h,
                                                     const float* __restrict__ a_s,
                                                     const float* __restrict__ a_d,
                                                     float* __restrict__ ls,
                                                     float* __restrict__ ld,
                                                     unsigned short* __restrict__ hb) {
    const int lane = threadIdx.x & 63;
    const int wid  = threadIdx.x >> 6;
    const int node = blockIdx.x * 4 + wid;
    if (node >= N_NODES) return;
    const int myh = lane >> 4;

    float4 v = *(const float4*)&h[(size_t)node * HID + lane * 4];
    ushort4 q;
    q.x = f2bf(v.x); q.y = f2bf(v.y); q.z = f2bf(v.z); q.w = f2bf(v.w);
    *(ushort4*)&hb[(size_t)node * HID + lane * 4] = q;

    const float4 as4 = *(const float4*)&a_s[lane * 4];
    const float4 ad4 = *(const float4*)&a_d[lane * 4];
    float ss = v.x * as4.x + v.y * as4.y + v.z * as4.z + v.w * as4.w;
    float dd = v.x * ad4.x + v.y * ad4.y + v.z * ad4.z + v.w * ad4.w;
    #pragma unroll
    for (int o = 1; o < 16; o <<= 1) {
        ss += __shfl_xor(ss, o);
        dd += __shfl_xor(dd, o);
    }
    if ((lane & 15) == 0) {
        ls[node * HEADS + myh] = ss;
        ld[node * HEADS + myh] = dd;
    }
}

// --------------------------------------------------------- GAT aggregation
__device__ __forceinline__ float leaky(float x) { return fmaxf(x, NEG_SLOPE * x); }

template <bool RELU>
__global__ __launch_bounds__(256) void gat_aggregate(const unsigned short* __restrict__ hb,
                                                     const int* __restrict__ off,
                                                     const int* __restrict__ ssrc,
                                                     const float* __restrict__ ls,
                                                     const float* __restrict__ ld,
                                                     const float* __restrict__ bias,
                                                     float* __restrict__ h_out) {
    const int lane = threadIdx.x & 63;
    const int wid  = threadIdx.x >> 6;
    const int node = blockIdx.x * 4 + wid;
    if (node >= N_NODES) return;
    const int lo = off[node], hi = off[node + 1];
    const int myh = lane >> 4;
    const float ldv = ld[node * HEADS + myh];

    float4 acc = make_float4(0.f, 0.f, 0.f, 0.f);
    float den = 0.f;
    int e = lo;
    for (; e + 4 <= hi; e += 4) {              // unroll-4: 4 gathers in flight
        int s0 = ssrc[e],     s1 = ssrc[e + 1];
        int s2 = ssrc[e + 2], s3 = ssrc[e + 3];
        float l0 = ls[s0 * HEADS + myh], l1 = ls[s1 * HEADS + myh];
        float l2 = ls[s2 * HEADS + myh], l3 = ls[s3 * HEADS + myh];
        ushort4 q0 = *(const ushort4*)&hb[(size_t)s0 * HID + lane * 4];
        ushort4 q1 = *(const ushort4*)&hb[(size_t)s1 * HID + lane * 4];
        ushort4 q2 = *(const ushort4*)&hb[(size_t)s2 * HID + lane * 4];
        ushort4 q3 = *(const ushort4*)&hb[(size_t)s3 * HID + lane * 4];
        float w0 = __expf(leaky(l0 + ldv)), w1 = __expf(leaky(l1 + ldv));
        float w2 = __expf(leaky(l2 + ldv)), w3 = __expf(leaky(l3 + ldv));
        den += (w0 + w1) + (w2 + w3);
        acc.x += w0 * bf2f(q0.x) + w1 * bf2f(q1.x) + w2 * bf2f(q2.x) + w3 * bf2f(q3.x);
        acc.y += w0 * bf2f(q0.y) + w1 * bf2f(q1.y) + w2 * bf2f(q2.y) + w3 * bf2f(q3.y);
        acc.z += w0 * bf2f(q0.z) + w1 * bf2f(q1.z) + w2 * bf2f(q2.z) + w3 * bf2f(q3.z);
        acc.w += w0 * bf2f(q0.w) + w1 * bf2f(q1.w) + w2 * bf2f(q2.w) + w3 * bf2f(q3.w);
    }
    for (; e < hi; ++e) {
        int s0 = ssrc[e];
        float w0 = __expf(leaky(ls[s0 * HEADS + myh] + ldv));
        ushort4 q0 = *(const ushort4*)&hb[(size_t)s0 * HID + lane * 4];
        den += w0;
        acc.x += w0 * bf2f(q0.x); acc.y += w0 * bf2f(q0.y);
        acc.z += w0 * bf2f(q0.z); acc.w += w0 * bf2f(q0.w);
    }
    float inv = 1.f / (den + 1e-16f);
    float4 bv = *(const float4*)(bias + lane * 4);
    float4 o;
    o.x = acc.x * inv + bv.x; o.y = acc.y * inv + bv.y;
    o.z = acc.z * inv + bv.z; o.w = acc.w * inv + bv.w;
    if (RELU) {
        o.x = fmaxf(o.x, 0.f); o.y = fmaxf(o.y, 0.f);
        o.z = fmaxf(o.z, 0.f); o.w = fmaxf(o.w, 0.f);
    }
    *(float4*)(h_out + (size_t)node * HID + lane * 4) = o;
}

// ---------------------------------------------------------------- pooling
__global__ __launch_bounds__(256) void pool_kernel(const float* __restrict__ h,
                                                   const int* __restrict__ batch,
                                                   float* __restrict__ pooled) {
    const int g = blockIdx.x;
    __shared__ int bounds[2];
    if (threadIdx.x < 2) {
        int target = g + threadIdx.x;
        int lo = 0, hi = N_NODES;
        while (lo < hi) {
            int mid = (lo + hi) >> 1;
            if (batch[mid] < target) lo = mid + 1; else hi = mid;
        }
        bounds[threadIdx.x] = lo;
    }
    __syncthreads();
    const int lo = bounds[0], hi = bounds[1];
    const int c = threadIdx.x;
    float s = 0.f;
    for (int i = lo; i < hi; ++i) s += h[(size_t)i * HID + c];
    float cnt = (float)max(hi - lo, 1);
    pooled[(size_t)g * HID + c] = s / cnt;
}

// -------------------------------------------------------------- layernorm
__global__ __launch_bounds__(256) void ln_kernel(const float* __restrict__ z2p,
                                                 const float* __restrict__ bm2,
                                                 const float* __restrict__ gamma,
                                                 const float* __restrict__ beta,
                                                 float* __restrict__ out) {
    const int row = blockIdx.x;
    float v[3];
    float s = 0.f, s2 = 0.f;
    #pragma unroll
    for (int i = 0; i < 3; ++i) {
        int c = threadIdx.x + i * 256;
        float a = bm2[c];
        #pragma unroll
        for (int sp = 0; sp < KSPL; ++sp)
            a += z2p[(size_t)sp * NGRAPH * NOUT + (size_t)row * NOUT + c];
        v[i] = a;
        s += a;
        s2 += a * a;
    }
    #pragma unroll
    for (int o = 32; o > 0; o >>= 1) {
        s  += __shfl_down(s, o);
        s2 += __shfl_down(s2, o);
    }
    __shared__ float red[8];
    const int wid = threadIdx.x >> 6, lane = threadIdx.x & 63;
    if (lane == 0) { red[wid] = s; red[4 + wid] = s2; }
    __syncthreads();
    if (threadIdx.x == 0) {
        float S  = red[0] + red[1] + red[2] + red[3];
        float S2 = red[4] + red[5] + red[6] + red[7];
        float mu  = S / NOUT;
        float var = S2 / NOUT - mu * mu;
        red[0] = mu;
        red[1] = rsqrtf(var + 1e-5f);
    }
    __syncthreads();
    float mu = red[0], rstd = red[1];
    #pragma unroll
    for (int i = 0; i < 3; ++i) {
        int c = threadIdx.x + i * 256;
        out[(size_t)row * NOUT + c] = gamma[c] * (v[i] - mu) * rstd + beta[c];
    }
}

// ------------------------------------------------------------------ launch
extern "C" void kernel_launch(void* const* d_in, const int* in_sizes, int n_in,
                              void* d_out, int out_size, void* d_ws, size_t ws_size,
                              hipStream_t stream) {
    const float* x     = (const float*)d_in[0];
    const int*   ei    = (const int*)d_in[1];
    const int*   batch = (const int*)d_in[2];
    const float* W1    = (const float*)d_in[3];
    const float* a_s1  = (const float*)d_in[4];
    const float* a_d1  = (const float*)d_in[5];
    const float* b1    = (const float*)d_in[6];
    const float* W2    = (const float*)d_in[7];
    const float* a_s2  = (const float*)d_in[8];
    const float* a_d2  = (const float*)d_in[9];
    const float* b2    = (const float*)d_in[10];
    const float* W3    = (const float*)d_in[11];
    const float* a_s3  = (const float*)d_in[12];
    const float* a_d3  = (const float*)d_in[13];
    const float* b3    = (const float*)d_in[14];
    const float* Wm1   = (const float*)d_in[15];
    const float* bm1   = (const float*)d_in[16];
    const float* Wm2   = (const float*)d_in[17];
    const float* bm2   = (const float*)d_in[18];
    const float* gamma = (const float*)d_in[19];
    const float* beta  = (const float*)d_in[20];
    float* out = (float*)d_out;

    char* p = (char*)d_ws;
    auto alloc = [&](size_t bytes) {
        void* r = (void*)p;
        p += (bytes + 255) & ~(size_t)255;
        return r;
    };
    int*   deg    = (int*)  alloc((size_t)N_NODES * 4);
    int*   off    = (int*)  alloc((size_t)(N_NODES + 1) * 4);
    int*   cur    = (int*)  alloc((size_t)N_NODES * 4);
    int*   ssrc   = (int*)  alloc((size_t)N_ETOT * 4);
    int*   bsum   = (int*)  alloc((size_t)256 * 4);
    int*   bpre   = (int*)  alloc((size_t)256 * 4);
    float* ls     = (float*)alloc((size_t)N_NODES * HEADS * 4);
    float* ld     = (float*)alloc((size_t)N_NODES * HEADS * 4);
    float* hA     = (float*)alloc((size_t)N_NODES * HID * 4);
    float* hB     = (float*)alloc((size_t)N_NODES * HID * 4);
    unsigned short* hb  = (unsigned short*)alloc((size_t)N_NODES * HID * 2);
    unsigned short* W2t = (unsigned short*)alloc((size_t)HID * HID * 2);
    unsigned short* W3t = (unsigned short*)alloc((size_t)HID * HID * 2);
    float* pooled = (float*)alloc((size_t)NGRAPH * HID * 4);
    float* z1     = (float*)alloc((size_t)NGRAPH * MLP_HID * 4);
    float* z2p    = (float*)alloc((size_t)KSPL * NGRAPH * NOUT * 4);

    // ---- CSR by dst (3-phase parallel scan) + weight transposes
    hipMemsetAsync(deg, 0, (size_t)N_NODES * 4, stream);
    hist_kernel<<<(N_ETOT + 255) / 256, 256, 0, stream>>>(ei, deg);
    bsum_kernel<<<NBLK, 256, 0, stream>>>(deg, bsum);
    bscan_kernel<<<1, 256, 0, stream>>>(bsum, bpre, off);
    cscan_kernel<<<NBLK, 256, 0, stream>>>(deg, bpre, off, cur);
    scatter_kernel<<<(N_ETOT + 255) / 256, 256, 0, stream>>>(ei, cur, ssrc);
    castT_kernel<<<HID, 256, 0, stream>>>(W2, W2t);
    castT_kernel<<<HID, 256, 0, stream>>>(W3, W3t);

    const int nodeBlocks = (N_NODES + 3) / 4;
    dim3 mfmaGrid((N_NODES + 63) / 64, HEADS);      // 782 x 4 (bn tile = head)

    // ---- layer 1 (K=32: fp32 GEMM + separate logits)
    dim3 gemmN((N_NODES + 127) / 128, HID / 128);
    gemm_kernel<128, 128, 8, 8, false, false, false><<<gemmN, 256, 0, stream>>>(x, W1, nullptr, hA, N_NODES, HID, F_IN, F_IN);
    logits_kernel<<<nodeBlocks, 256, 0, stream>>>(hA, a_s1, a_d1, ls, ld, hb);
    gat_aggregate<true><<<nodeBlocks, 256, 0, stream>>>(hb, off, ssrc, ls, ld, b1, hB);

    // ---- layer 2 (MFMA bf16, fused logits+pack)
    gemm_mfma_fused<<<mfmaGrid, 256, 0, stream>>>(hB, W2t, a_s2, a_d2, hb, ls, ld, N_NODES);
    gat_aggregate<true><<<nodeBlocks, 256, 0, stream>>>(hb, off, ssrc, ls, ld, b2, hB);

    // ---- layer 3 (MFMA bf16, fused logits+pack, no relu)
    gemm_mfma_fused<<<mfmaGrid, 256, 0, stream>>>(hB, W3t, a_s3, a_d3, hb, ls, ld, N_NODES);
    gat_aggregate<false><<<nodeBlocks, 256, 0, stream>>>(hb, off, ssrc, ls, ld, b3, hB);

    // ---- pool + MLP + layernorm (fp32 paths)
    pool_kernel<<<NGRAPH, 256, 0, stream>>>(hB, batch, pooled);
    dim3 gm1(NGRAPH / 64, MLP_HID / 128);
    gemm_kernel<64, 128, 4, 8, true, true, false><<<gm1, 256, 0, stream>>>(pooled, Wm1, bm1, z1, NGRAPH, MLP_HID, HID, HID);
    dim3 gm2(NGRAPH / 64, NOUT / 64, KSPL);
    gemm_kernel<64, 64, 4, 4, false, false, true><<<gm2, 256, 0, stream>>>(z1, Wm2, nullptr, z2p, NGRAPH, NOUT, MLP_HID / KSPL, MLP_HID);
    ln_kernel<<<NGRAPH, 256, 0, stream>>>(z2p, bm2, gamma, beta, out);
}